// Round 11
// baseline (863.966 us; speedup 1.0000x reference)
//
#include <hip/hip_runtime.h>
#include <hip/hip_bf16.h>

#define N_NODES 100000
#define N_EDGES 1600000
#define G_GRAPHS 64
#define D_IN 128
#define POS_DIM 16
#define HID 32
#define HEADS 4
#define OUT_DIM 10
#define D0 144
#define D1 128
#define LRELU_SLOPE 0.2f
#define BN_EPS 1e-5f
#define DIV_W 0.1f

#define BK_SHIFT 9
#define BK_NODES 512
#define NB 196
#define TILE_E 4096
#define NTILES ((N_EDGES + TILE_E - 1) / TILE_E)

#define K0P 160

typedef __attribute__((ext_vector_type(8))) short short8v;
typedef __attribute__((ext_vector_type(4))) float f32x4;

__device__ __forceinline__ unsigned short f2b(float f) {
    unsigned u = __float_as_uint(f);
    unsigned r = (u + 0x7FFFu + ((u >> 16) & 1u)) >> 16;
    return (unsigned short)r;
}
__device__ __forceinline__ float blo(unsigned v) { return __uint_as_float(v << 16); }
__device__ __forceinline__ float bhi(unsigned v) { return __uint_as_float(v & 0xFFFF0000u); }

// ---------------- histogram of batch -> counts[64] ----------------
__global__ void k_hist(const int* __restrict__ batch, int* __restrict__ counts, int n) {
    __shared__ int hist[G_GRAPHS];
    if (threadIdx.x < G_GRAPHS) hist[threadIdx.x] = 0;
    __syncthreads();
    for (int i = blockIdx.x * blockDim.x + threadIdx.x; i < n; i += gridDim.x * blockDim.x)
        atomicAdd(&hist[batch[i]], 1);
    __syncthreads();
    if (threadIdx.x < G_GRAPHS) atomicAdd(&counts[threadIdx.x], hist[threadIdx.x]);
}

__global__ void k_gridstats(const int* __restrict__ counts, int* __restrict__ starts,
                            int* __restrict__ gridg) {
    if (threadIdx.x == 0) {
        int run = 0;
        for (int g = 0; g < G_GRAPHS; ++g) {
            starts[g] = run;
            int c = counts[g];
            run += c;
            int s = (int)sqrtf((float)c);
            while ((long long)s * s < c) ++s;
            while (s > 0 && (long long)(s - 1) * (s - 1) >= c) --s;
            gridg[g] = s;
        }
    }
}

__global__ void k_pos(const int* __restrict__ batch, const int* __restrict__ starts,
                      const int* __restrict__ gridg, float2* __restrict__ pos2) {
    int t = blockIdx.x * blockDim.x + threadIdx.x;
    if (t >= N_NODES) return;
    int b = batch[t];
    int local = t - starts[b];
    int g = max(gridg[b], 1);
    float denom = (float)max(g - 1, 1);
    int r = local / g;
    int c = local - r * g;
    pos2[t] = make_float2((float)r / denom, (float)c / denom);
}

// ---------------- weight prep: bf16 transposed [col][K] ----------------
__global__ void k_wprep(const float* __restrict__ w0, const float* __restrict__ w1,
                        const float* __restrict__ wr, unsigned short* __restrict__ t0,
                        unsigned short* __restrict__ t1, unsigned short* __restrict__ tr) {
    int t = blockIdx.x * 256 + threadIdx.x;
    if (t < 128 * K0P) {
        int c = t / K0P, k = t % K0P;
        t0[t] = (k < D0) ? f2b(w0[k * 128 + c]) : (unsigned short)0;
    } else if (t < 128 * K0P + 128 * 128) {
        int i = t - 128 * K0P;
        int c = i / 128, k = i % 128;
        t1[i] = f2b(w1[k * 128 + c]);
    } else if (t < 128 * K0P + 2 * 128 * 128) {
        int i = t - 128 * K0P - 128 * 128;
        int c = i / 128, k = i % 128;
        tr[i] = f2b(wr[k * 128 + c]);
    }
}

// ---------------- bucket histogram over dst ----------------
__global__ void k_bhist(const int* __restrict__ ei, int* __restrict__ bcount) {
    __shared__ int lh[256];
    int tid = threadIdx.x;
    lh[tid] = 0;
    __syncthreads();
    int e = (blockIdx.x * blockDim.x + tid) * 4;
    if (e < N_EDGES) {
        int4 d4 = *reinterpret_cast<const int4*>(ei + N_EDGES + e);
        atomicAdd(&lh[d4.x >> BK_SHIFT], 1);
        atomicAdd(&lh[d4.y >> BK_SHIFT], 1);
        atomicAdd(&lh[d4.z >> BK_SHIFT], 1);
        atomicAdd(&lh[d4.w >> BK_SHIFT], 1);
    }
    __syncthreads();
    if (tid < NB && lh[tid] > 0) atomicAdd(&bcount[tid], lh[tid]);
}

__global__ void k_bscan(const int* __restrict__ bcount, int* __restrict__ bstart,
                        int* __restrict__ bcursor) {
    if (threadIdx.x == 0) {
        int run = 0;
        for (int i = 0; i < NB; ++i) {
            bstart[i] = run;
            bcursor[i] = run;
            run += bcount[i];
        }
        bstart[NB] = run;
    }
}

// ---------------- tile-local counting sort -> bucket-major pairs (shfl scan) ----------------
__global__ __launch_bounds__(256) void k_bucket(const int* __restrict__ ei,
                                                int* __restrict__ bcursor,
                                                int2* __restrict__ pairs) {
    __shared__ int lh[256];
    __shared__ int lstart[256];
    __shared__ int lcur[256];
    __shared__ int gbase[256];
    __shared__ int wsum[4];
    __shared__ int2 stage[TILE_E];
    const int tid = threadIdx.x;
    const int lane = tid & 63;
    const int wid = tid >> 6;
    const int tile = blockIdx.x * TILE_E;
    const int cnt = min(TILE_E, N_EDGES - tile);
    lh[tid] = 0;
    __syncthreads();
    int sv[16], dv[16];
#pragma unroll
    for (int u = 0; u < 16; ++u) {
        int i = u * 256 + tid;
        if (i < cnt) {
            sv[u] = ei[tile + i];
            dv[u] = ei[N_EDGES + tile + i];
            atomicAdd(&lh[dv[u] >> BK_SHIFT], 1);
        } else {
            sv[u] = -1; dv[u] = -1;
        }
    }
    __syncthreads();
    int own = lh[tid];
    int incl = own;
#pragma unroll
    for (int off = 1; off < 64; off <<= 1) {
        int t = __shfl_up(incl, off, 64);
        if (lane >= off) incl += t;
    }
    if (lane == 63) wsum[wid] = incl;
    __syncthreads();
    int wo = 0;
#pragma unroll
    for (int w = 0; w < 3; ++w) if (w < wid) wo += wsum[w];
    int excl = incl - own + wo;
    lstart[tid] = excl;
    lcur[tid] = excl;
    __syncthreads();
#pragma unroll
    for (int u = 0; u < 16; ++u) {
        if (dv[u] >= 0) {
            int b = dv[u] >> BK_SHIFT;
            int slot = atomicAdd(&lcur[b], 1);
            stage[slot] = make_int2(sv[u], dv[u]);
        }
    }
    __syncthreads();
    if (tid < NB && own > 0) gbase[tid] = atomicAdd(&bcursor[tid], own);
    __syncthreads();
    for (int i = tid; i < cnt; i += 256) {
        int2 pr = stage[i];
        int b = pr.y >> BK_SHIFT;
        pairs[gbase[b] + (i - lstart[b])] = pr;
    }
}

// ---------------- per-bucket CSR finalize (shfl scan) ----------------
__global__ __launch_bounds__(256) void k_csr(const int2* __restrict__ pairs,
                                             const int* __restrict__ bstart,
                                             int* __restrict__ offs,
                                             int* __restrict__ csr_src) {
    __shared__ int ldeg[BK_NODES];
    __shared__ int lcur[BK_NODES];
    __shared__ int wsum[4];
    const int b = blockIdx.x;
    const int tid = threadIdx.x;
    const int lane = tid & 63;
    const int wid = tid >> 6;
    const int nb0 = b * BK_NODES;
    const int base = bstart[b];
    const int ecnt = bstart[b + 1] - base;
    ldeg[tid] = 0; ldeg[tid + 256] = 0;
    __syncthreads();
    for (int i = tid; i < ecnt; i += 256)
        atomicAdd(&ldeg[pairs[base + i].y - nb0], 1);
    __syncthreads();
    int v0 = ldeg[tid * 2], v1 = ldeg[tid * 2 + 1];
    int tsum = v0 + v1;
    int incl = tsum;
#pragma unroll
    for (int off = 1; off < 64; off <<= 1) {
        int t = __shfl_up(incl, off, 64);
        if (lane >= off) incl += t;
    }
    if (lane == 63) wsum[wid] = incl;
    __syncthreads();
    int wo = 0;
#pragma unroll
    for (int w = 0; w < 3; ++w) if (w < wid) wo += wsum[w];
    int excl = incl - tsum + wo;
    int o0 = base + excl;
    int o1 = o0 + v0;
    lcur[tid * 2] = o0;
    lcur[tid * 2 + 1] = o1;
    int n0 = nb0 + tid * 2, n1 = n0 + 1;
    if (n0 < N_NODES) offs[n0] = o0;
    if (n1 < N_NODES) offs[n1] = o1;
    if (b == NB - 1 && tid == 0) offs[N_NODES] = bstart[NB];
    __syncthreads();
    for (int i = tid; i < ecnt; i += 256) {
        int2 pr = pairs[base + i];
        int pos = atomicAdd(&lcur[pr.y - nb0], 1);
        csr_src[pos] = pr.x;
    }
}

// ---------------- MFMA GEMM: 64 rows x 128 cols / block ----------------
template <int K, int POS, int RES, int BF16A>
__global__ __launch_bounds__(256) void k_gemm3(
        const float* __restrict__ in, const unsigned short* __restrict__ inb,
        const float2* __restrict__ pos2,
        const float* __restrict__ posw, const float* __restrict__ posb,
        const unsigned short* __restrict__ wbT,
        const float* __restrict__ asrc, const float* __restrict__ adst,
        float* __restrict__ es, float* __restrict__ ed,
        unsigned short* __restrict__ outb,
        const unsigned short* __restrict__ wbT2, const float* __restrict__ bias2,
        unsigned short* __restrict__ outb2, int n) {
    __shared__ unsigned short At[64 * K];
    const int tid = threadIdx.x;
    const int base = blockIdx.x * 64;
    if (BF16A) {
        constexpr int KC8 = K / 8;
        for (int idx = tid; idx < 64 * KC8; idx += 256) {
            int row = idx / KC8, g = idx % KC8;
            int grow = base + row;
            short8v v = (short8v)(short)0;
            if (grow < n) v = *reinterpret_cast<const short8v*>(inb + (size_t)grow * 128 + g * 8);
            unsigned byteoff = (unsigned)((row * K + g * 8) * 2) ^ (unsigned)((row & 7) << 4);
            *reinterpret_cast<short8v*>(reinterpret_cast<char*>(At) + byteoff) = v;
        }
    } else {
        constexpr int KC4 = K / 4;
        for (int idx = tid; idx < 64 * KC4; idx += 256) {
            int row = idx / KC4, c4 = idx % KC4;
            int grow = base + row;
            float4 v = make_float4(0.f, 0.f, 0.f, 0.f);
            if (grow < n) {
                if (!POS || c4 < 32) {
                    v = reinterpret_cast<const float4*>(in)[(size_t)grow * 32 + c4];
                } else if (c4 < 36) {
                    float2 p = pos2[grow];
                    int q = c4 - 32;
                    float4 w0v = reinterpret_cast<const float4*>(posw)[q];
                    float4 w1v = reinterpret_cast<const float4*>(posw + POS_DIM)[q];
                    float4 bv  = reinterpret_cast<const float4*>(posb)[q];
                    v.x = fmaf(p.x, w0v.x, fmaf(p.y, w1v.x, bv.x));
                    v.y = fmaf(p.x, w0v.y, fmaf(p.y, w1v.y, bv.y));
                    v.z = fmaf(p.x, w0v.z, fmaf(p.y, w1v.z, bv.z));
                    v.w = fmaf(p.x, w0v.w, fmaf(p.y, w1v.w, bv.w));
                }
            }
            ushort4 b4;
            b4.x = f2b(v.x); b4.y = f2b(v.y); b4.z = f2b(v.z); b4.w = f2b(v.w);
            unsigned byteoff = (unsigned)((row * K + c4 * 4) * 2) ^ (unsigned)((row & 7) << 4);
            *reinterpret_cast<ushort4*>(reinterpret_cast<char*>(At) + byteoff) = b4;
        }
    }
    __syncthreads();

    const int wv = tid >> 6;
    const int lane = tid & 63;
    const int lrow = lane & 15;
    const int lk8 = lane >> 4;
    f32x4 acc[4][2];
    f32x4 acc2[RES ? 4 : 1][RES ? 2 : 1];
#pragma unroll
    for (int rt = 0; rt < 4; ++rt) {
#pragma unroll
        for (int ct = 0; ct < 2; ++ct) {
            acc[rt][ct] = (f32x4){0.f, 0.f, 0.f, 0.f};
            if (RES) acc2[rt][ct] = (f32x4){0.f, 0.f, 0.f, 0.f};
        }
    }
    const unsigned short* bp0 = wbT + (size_t)(wv * 32 + lrow) * K + lk8 * 8;
    const unsigned short* bp1 = bp0 + 16 * K;
    const unsigned short* cp0 = RES ? (wbT2 + (size_t)(wv * 32 + lrow) * K + lk8 * 8) : nullptr;
    const unsigned short* cp1 = RES ? cp0 + 16 * K : nullptr;

    for (int k0 = 0; k0 < K; k0 += 32) {
        short8v b0 = *reinterpret_cast<const short8v*>(bp0 + k0);
        short8v b1 = *reinterpret_cast<const short8v*>(bp1 + k0);
        short8v a[4];
#pragma unroll
        for (int rt = 0; rt < 4; ++rt) {
            int row = rt * 16 + lrow;
            unsigned byteoff = (unsigned)((row * K + k0 + lk8 * 8) * 2) ^ (unsigned)((row & 7) << 4);
            a[rt] = *reinterpret_cast<const short8v*>(reinterpret_cast<const char*>(At) + byteoff);
        }
#pragma unroll
        for (int rt = 0; rt < 4; ++rt) {
            acc[rt][0] = __builtin_amdgcn_mfma_f32_16x16x32_bf16(a[rt], b0, acc[rt][0], 0, 0, 0);
            acc[rt][1] = __builtin_amdgcn_mfma_f32_16x16x32_bf16(a[rt], b1, acc[rt][1], 0, 0, 0);
        }
        if (RES) {
            short8v c0 = *reinterpret_cast<const short8v*>(cp0 + k0);
            short8v c1 = *reinterpret_cast<const short8v*>(cp1 + k0);
#pragma unroll
            for (int rt = 0; rt < 4; ++rt) {
                acc2[rt][0] = __builtin_amdgcn_mfma_f32_16x16x32_bf16(a[rt], c0, acc2[rt][0], 0, 0, 0);
                acc2[rt][1] = __builtin_amdgcn_mfma_f32_16x16x32_bf16(a[rt], c1, acc2[rt][1], 0, 0, 0);
            }
        }
    }

    float av0 = asrc[wv * 32 + lrow], av1 = asrc[wv * 32 + 16 + lrow];
    float dv0 = adst[wv * 32 + lrow], dv1 = adst[wv * 32 + 16 + lrow];
    float bb0 = 0.f, bb1 = 0.f;
    if (RES) { bb0 = bias2[wv * 32 + lrow]; bb1 = bias2[wv * 32 + 16 + lrow]; }
#pragma unroll
    for (int rt = 0; rt < 4; ++rt) {
#pragma unroll
        for (int r = 0; r < 4; ++r) {
            int row = rt * 16 + lk8 * 4 + r;
            int grow = base + row;
            bool live = (grow < n);
            float v0 = acc[rt][0][r], v1 = acc[rt][1][r];
            if (live) {
                outb[(size_t)grow * 128 + wv * 32 + lrow] = f2b(v0);
                outb[(size_t)grow * 128 + wv * 32 + 16 + lrow] = f2b(v1);
                if (RES) {
                    outb2[(size_t)grow * 128 + wv * 32 + lrow] = f2b(acc2[rt][0][r] + bb0);
                    outb2[(size_t)grow * 128 + wv * 32 + 16 + lrow] = f2b(acc2[rt][1][r] + bb1);
                }
            }
            float ps = v0 * av0 + v1 * av1;
            float pd = v0 * dv0 + v1 * dv1;
            ps += __shfl_xor(ps, 1); pd += __shfl_xor(pd, 1);
            ps += __shfl_xor(ps, 2); pd += __shfl_xor(pd, 2);
            ps += __shfl_xor(ps, 4); pd += __shfl_xor(pd, 4);
            ps += __shfl_xor(ps, 8); pd += __shfl_xor(pd, 8);
            if (lrow == 0 && live) {
                es[grow * 4 + wv] = ps;
                ed[grow * 4 + wv] = pd;
            }
        }
    }
}

// ---------------- CSR aggregation: 1 node / wave, scalar-load edge metadata ----------------
__global__ void k_aggb(const int* __restrict__ csr_src, const int* __restrict__ offs,
                       const float* __restrict__ es, const float* __restrict__ ed,
                       const unsigned* __restrict__ hb32, const float* __restrict__ bias,
                       float* __restrict__ out) {
    const int wv = __builtin_amdgcn_readfirstlane(threadIdx.x >> 6);
    const int node = blockIdx.x * 4 + wv;
    if (node >= N_NODES) return;
    const int lane = threadIdx.x & 63;
    const int hd = lane >> 4;
    const bool h1 = (hd & 1) != 0;
    const bool h2 = (hd & 2) != 0;
    // ed row: uniform address -> scalar load; per-lane head select
    float4 edr = reinterpret_cast<const float4*>(ed)[node];
    float ed01 = h1 ? edr.y : edr.x;
    float ed23 = h1 ? edr.w : edr.z;
    float edv = h2 ? ed23 : ed01;
    int rs = offs[node], re_ = offs[node + 1];   // uniform -> scalar
    float ax[4] = {0.f, 0.f, 0.f, 0.f};
    float ay[4] = {0.f, 0.f, 0.f, 0.f};
    float ds[4] = {0.f, 0.f, 0.f, 0.f};
    int j = rs;
    for (; j + 8 <= re_; j += 8) {
        int s[8];
#pragma unroll
        for (int u = 0; u < 8; ++u)
            s[u] = __builtin_amdgcn_readfirstlane(csr_src[j + u]);   // force uniform
        float4 r[8];
#pragma unroll
        for (int u = 0; u < 8; ++u)
            r[u] = reinterpret_cast<const float4*>(es)[s[u]];        // uniform -> scalar x4
        unsigned q[8];
#pragma unroll
        for (int u = 0; u < 8; ++u)
            q[u] = hb32[(size_t)s[u] * 64 + lane];                   // the real gather
#pragma unroll
        for (int u = 0; u < 8; ++u) {
            float e01 = h1 ? r[u].y : r[u].x;
            float e23 = h1 ? r[u].w : r[u].z;
            float a = (h2 ? e23 : e01) + edv;
            a = (a > 0.f) ? a : LRELU_SLOPE * a;
            float x = __expf(a);
            ax[u & 3] = fmaf(x, blo(q[u]), ax[u & 3]);
            ay[u & 3] = fmaf(x, bhi(q[u]), ay[u & 3]);
            ds[u & 3] += x;
        }
    }
    for (; j < re_; ++j) {
        int s = __builtin_amdgcn_readfirstlane(csr_src[j]);
        float4 r = reinterpret_cast<const float4*>(es)[s];
        float e01 = h1 ? r.y : r.x;
        float e23 = h1 ? r.w : r.z;
        float a = (h2 ? e23 : e01) + edv;
        a = (a > 0.f) ? a : LRELU_SLOPE * a;
        float x = __expf(a);
        unsigned hv = hb32[(size_t)s * 64 + lane];
        ax[0] = fmaf(x, blo(hv), ax[0]);
        ay[0] = fmaf(x, bhi(hv), ay[0]);
        ds[0] += x;
    }
    {   // self loop
        float4 r = reinterpret_cast<const float4*>(es)[node];
        float e01 = h1 ? r.y : r.x;
        float e23 = h1 ? r.w : r.z;
        float a = (h2 ? e23 : e01) + edv;
        a = (a > 0.f) ? a : LRELU_SLOPE * a;
        float x = __expf(a);
        unsigned hv = hb32[(size_t)node * 64 + lane];
        ax[0] = fmaf(x, blo(hv), ax[0]);
        ay[0] = fmaf(x, bhi(hv), ay[0]);
        ds[0] += x;
    }
    float inv = 1.f / (ds[0] + ds[1] + ds[2] + ds[3]);
    float2 o;
    o.x = fmaf(ax[0] + ax[1] + ax[2] + ax[3], inv, bias[lane * 2]);
    o.y = fmaf(ay[0] + ay[1] + ay[2] + ay[3], inv, bias[lane * 2 + 1]);
    reinterpret_cast<float2*>(out)[(size_t)node * 64 + lane] = o;
}

// ---------------- div loss + BN + ELU; LAYER0 -> bf16 h0; LAYER1 -> +res, pool, no store --
template <int LAYER>
__global__ __launch_bounds__(256) void k_divbn(
        const float* __restrict__ hin, const unsigned* __restrict__ rbuf16,
        const float* __restrict__ proj, const float* __restrict__ gamma,
        const float* __restrict__ beta, const float* __restrict__ mean,
        const float* __restrict__ var, float* __restrict__ Msum,
        unsigned* __restrict__ outb16,
        const int* __restrict__ batch, float* __restrict__ emb) {
    __shared__ float sm[6];
    const int tid = threadIdx.x;
    if (tid < 6) sm[tid] = 0.f;
    __syncthreads();
    const int lane = tid & 63;
    const int wid = tid >> 6;
    const int wave_id = blockIdx.x * 4 + wid;
    const int CH = (N_NODES + 4095) / 4096;
    const int start = wave_id * CH;
    const int end = min(start + CH, N_NODES);
    float2 pj = reinterpret_cast<const float2*>(proj)[lane];
    float2 g2 = reinterpret_cast<const float2*>(gamma)[lane];
    float2 b2 = reinterpret_cast<const float2*>(beta)[lane];
    float2 m2 = reinterpret_cast<const float2*>(mean)[lane];
    float2 v2 = reinterpret_cast<const float2*>(var)[lane];
    float scx = g2.x * rsqrtf(v2.x + BN_EPS);
    float scy = g2.y * rsqrtf(v2.y + BN_EPS);
    float accA = 0.f, accB = 0.f, accC = 0.f;
    float ex = 0.f, ey = 0.f;
    int curg = -1;
    for (int node = start; node < end; ++node) {
        float2 hv = reinterpret_cast<const float2*>(hin)[(size_t)node * 64 + lane];
        float px = hv.x * pj.x, py = hv.y * pj.y;
        float nn = px * px + py * py;
        nn += __shfl_xor(nn, 1); nn += __shfl_xor(nn, 2);
        nn += __shfl_xor(nn, 4); nn += __shfl_xor(nn, 8);
        float tx = __shfl_xor(px, 16), ty = __shfl_xor(py, 16);
        float d16 = px * tx + py * ty;
        tx = __shfl_xor(px, 32); ty = __shfl_xor(py, 32);
        float d32 = px * tx + py * ty;
        tx = __shfl_xor(px, 48); ty = __shfl_xor(py, 48);
        float d48 = px * tx + py * ty;
        d16 += __shfl_xor(d16, 1); d16 += __shfl_xor(d16, 2);
        d16 += __shfl_xor(d16, 4); d16 += __shfl_xor(d16, 8);
        d32 += __shfl_xor(d32, 1); d32 += __shfl_xor(d32, 2);
        d32 += __shfl_xor(d32, 4); d32 += __shfl_xor(d32, 8);
        d48 += __shfl_xor(d48, 1); d48 += __shfl_xor(d48, 2);
        d48 += __shfl_xor(d48, 4); d48 += __shfl_xor(d48, 8);
        float n_own = fmaxf(sqrtf(nn), 1e-8f);
        float n16 = fmaxf(sqrtf(__shfl_xor(nn, 16)), 1e-8f);
        float n32 = fmaxf(sqrtf(__shfl_xor(nn, 32)), 1e-8f);
        float n48 = fmaxf(sqrtf(__shfl_xor(nn, 48)), 1e-8f);
        accA += d16 / (n_own * n16);
        accB += d32 / (n_own * n32);
        accC += d48 / (n_own * n48);
        float yx = (hv.x - m2.x) * scx + b2.x;
        float yy = (hv.y - m2.y) * scy + b2.y;
        yx = (yx > 0.f) ? yx : (__expf(yx) - 1.f);
        yy = (yy > 0.f) ? yy : (__expf(yy) - 1.f);
        if (LAYER == 1) {
            unsigned rb = rbuf16[(size_t)node * 64 + lane];
            yx += blo(rb);
            yy += bhi(rb);
            int g = batch[node];
            if (g != curg) {
                if (curg >= 0) {
                    unsafeAtomicAdd(&emb[curg * 128 + lane * 2], ex);
                    unsafeAtomicAdd(&emb[curg * 128 + lane * 2 + 1], ey);
                }
                curg = g; ex = 0.f; ey = 0.f;
            }
            ex += yx; ey += yy;
        } else {
            outb16[(size_t)node * 64 + lane] = (unsigned)f2b(yx) | ((unsigned)f2b(yy) << 16);
        }
    }
    if (LAYER == 1 && curg >= 0) {
        unsafeAtomicAdd(&emb[curg * 128 + lane * 2], ex);
        unsafeAtomicAdd(&emb[curg * 128 + lane * 2 + 1], ey);
    }
    int g = lane >> 4;
    if ((lane & 15) == 0) {
        if (g == 0) {
            atomicAdd(&sm[0], accA);
            atomicAdd(&sm[1], accB);
            atomicAdd(&sm[2], accC);
        } else if (g == 1) {
            atomicAdd(&sm[4], accB);
            atomicAdd(&sm[3], accC);
        } else if (g == 2) {
            atomicAdd(&sm[5], accA);
        }
    }
    __syncthreads();
    if (tid < 6) unsafeAtomicAdd(&Msum[tid], sm[tid]);
}

// ---------------- final: emb normalize, task head, div scalar ----------------
__global__ void k_final(const float* __restrict__ emb_ws, const int* __restrict__ counts,
                        const float* __restrict__ task_w, const float* __restrict__ task_b,
                        const float* __restrict__ Msum, float* __restrict__ out) {
    __shared__ float e_lds[G_GRAPHS * 128];
    __shared__ float cnt[G_GRAPHS];
    int tid = threadIdx.x;
    if (tid < G_GRAPHS) cnt[tid] = fmaxf((float)counts[tid], 1.f);
    __syncthreads();
    for (int i = tid; i < G_GRAPHS * 128; i += 256) {
        float v = emb_ws[i] / cnt[i >> 7];
        e_lds[i] = v;
        out[641 + i] = v;
    }
    __syncthreads();
    for (int p = tid; p < G_GRAPHS * OUT_DIM; p += 256) {
        int g = p / OUT_DIM, o = p % OUT_DIM;
        float acc = task_b[o];
#pragma unroll 8
        for (int k = 0; k < 128; ++k) acc = fmaf(e_lds[g * 128 + k], task_w[k * OUT_DIM + o], acc);
        out[p] = acc;
    }
    if (tid == 0) {
        float div = 0.f;
        for (int l = 0; l < 2; ++l) {
            float s = 0.f;
            for (int p = 0; p < 6; ++p) {
                float m = Msum[l * 6 + p] / (float)N_NODES;
                s = fmaf(m, m, s);
            }
            div += s / 6.f;
        }
        out[G_GRAPHS * OUT_DIM] = DIV_W * div;
    }
}

extern "C" void kernel_launch(void* const* d_in, const int* in_sizes, int n_in,
                              void* d_out, int out_size, void* d_ws, size_t ws_size,
                              hipStream_t stream) {
    const float* x      = (const float*)d_in[0];
    const int*   ei     = (const int*)d_in[1];
    const int*   batch  = (const int*)d_in[2];
    const float* pos_w  = (const float*)d_in[3];
    const float* pos_b  = (const float*)d_in[4];
    const float* w0     = (const float*)d_in[5];
    const float* asrc0  = (const float*)d_in[6];
    const float* adst0  = (const float*)d_in[7];
    const float* b0     = (const float*)d_in[8];
    const float* w1     = (const float*)d_in[9];
    const float* asrc1  = (const float*)d_in[10];
    const float* adst1  = (const float*)d_in[11];
    const float* b1     = (const float*)d_in[12];
    const float* bn_gamma = (const float*)d_in[13];
    const float* bn_beta  = (const float*)d_in[14];
    const float* bn_mean  = (const float*)d_in[15];
    const float* bn_var   = (const float*)d_in[16];
    const float* proj   = (const float*)d_in[17];
    const float* res_w  = (const float*)d_in[18];
    const float* res_b  = (const float*)d_in[19];
    const float* task_w = (const float*)d_in[20];
    const float* task_b = (const float*)d_in[21];
    float* out = (float*)d_out;

    // workspace layout
    unsigned short* wbT0 = (unsigned short*)d_ws;
    unsigned short* wbT1 = wbT0 + 128 * K0P;
    unsigned short* wbTr = wbT1 + 128 * 128;
    unsigned short* hb   = wbTr + 128 * 128;                   // N*128 bf16 (gemm out h)
    unsigned short* hb0  = hb + (size_t)N_NODES * 128;         // N*128 bf16 (layer0 act)
    unsigned short* bbuf = hb0 + (size_t)N_NODES * 128;        // N*128 bf16 (res proj)
    float* p = (float*)(bbuf + (size_t)N_NODES * 128);
    float* abuf = p; p += (size_t)N_NODES * D1;                // agg out (f32)
    float* es   = p; p += (size_t)N_NODES * 4;
    float* ed   = p; p += (size_t)N_NODES * 4;
    float2* pos2 = (float2*)p; p += (size_t)N_NODES * 2;
    float* emb  = p; p += G_GRAPHS * 128;
    float* Msum = p; p += 16;
    int* counts = (int*)p;
    int* starts  = counts + G_GRAPHS;
    int* gridg   = starts + G_GRAPHS;
    int* bcount  = gridg + G_GRAPHS;
    int* bstart  = bcount + NB;
    int* bcursor = bstart + NB + 1;
    int* offs    = bcursor + NB;
    int* csr_src = (int*)(((uintptr_t)(offs + N_NODES + 1) + 15) & ~(uintptr_t)15);
    int2* pairs  = (int2*)(csr_src + N_EDGES + 8);

    const int B = 256;

    hipMemsetAsync(counts, 0, G_GRAPHS * sizeof(int), stream);
    hipMemsetAsync(Msum, 0, 12 * sizeof(float), stream);
    hipMemsetAsync(bcount, 0, NB * sizeof(int), stream);
    hipMemsetAsync(emb, 0, G_GRAPHS * 128 * sizeof(float), stream);
    hipMemsetAsync(csr_src + N_EDGES, 0, 8 * sizeof(int), stream);
    k_hist<<<256, B, 0, stream>>>(batch, counts, N_NODES);
    k_gridstats<<<1, 64, 0, stream>>>(counts, starts, gridg);
    k_pos<<<(N_NODES + B - 1) / B, B, 0, stream>>>(batch, starts, gridg, pos2);
    k_wprep<<<(128 * K0P + 2 * 128 * 128 + 255) / 256, 256, 0, stream>>>(
        w0, w1, res_w, wbT0, wbT1, wbTr);

    // CSR build: bucketed two-pass sort
    k_bhist<<<(N_EDGES / 4 + B - 1) / B, B, 0, stream>>>(ei, bcount);
    k_bscan<<<1, 64, 0, stream>>>(bcount, bstart, bcursor);
    k_bucket<<<NTILES, B, 0, stream>>>(ei, bcursor, pairs);
    k_csr<<<NB, B, 0, stream>>>(pairs, bstart, offs, csr_src);

    const int GB = (N_NODES + 63) / 64;
    const int AB = (N_NODES + 3) / 4;

    // ---- layer 0 ----
    k_gemm3<K0P, 1, 0, 0><<<GB, 256, 0, stream>>>(
        x, nullptr, pos2, pos_w, pos_b, wbT0, asrc0, adst0, es, ed, hb,
        nullptr, nullptr, nullptr, N_NODES);
    k_aggb<<<AB, B, 0, stream>>>(csr_src, offs, es, ed, (const unsigned*)hb, b0, abuf);
    k_divbn<0><<<1024, B, 0, stream>>>(
        abuf, nullptr, proj, bn_gamma, bn_beta, bn_mean, bn_var, Msum,
        (unsigned*)hb0, nullptr, nullptr);

    // ---- layer 1 ----
    k_gemm3<D1, 0, 1, 1><<<GB, 256, 0, stream>>>(
        nullptr, hb0, nullptr, nullptr, nullptr, wbT1, asrc1, adst1, es, ed, hb,
        wbTr, res_b, bbuf, N_NODES);
    k_aggb<<<AB, B, 0, stream>>>(csr_src, offs, es, ed, (const unsigned*)hb, b1, abuf);
    k_divbn<1><<<1024, B, 0, stream>>>(
        abuf, (const unsigned*)bbuf, proj + HEADS * HID, bn_gamma + D1, bn_beta + D1,
        bn_mean + D1, bn_var + D1, Msum + 6, nullptr, batch, emb);

    // heads
    k_final<<<1, B, 0, stream>>>(emb, counts, task_w, task_b, Msum, out);
}

// Round 12
// 501.981 us; speedup vs baseline: 1.7211x; 1.7211x over previous
//
#include <hip/hip_runtime.h>
#include <hip/hip_bf16.h>

#define N_NODES 100000
#define N_EDGES 1600000
#define G_GRAPHS 64
#define D_IN 128
#define POS_DIM 16
#define HID 32
#define HEADS 4
#define OUT_DIM 10
#define D0 144
#define D1 128
#define LRELU_SLOPE 0.2f
#define BN_EPS 1e-5f
#define DIV_W 0.1f

#define BK_SHIFT 9
#define BK_NODES 512
#define NB 196
#define TILE_E 4096
#define NTILES ((N_EDGES + TILE_E - 1) / TILE_E)

#define K0P 160

typedef __attribute__((ext_vector_type(8))) short short8v;
typedef __attribute__((ext_vector_type(4))) float f32x4;

__device__ __forceinline__ unsigned short f2b(float f) {
    unsigned u = __float_as_uint(f);
    unsigned r = (u + 0x7FFFu + ((u >> 16) & 1u)) >> 16;
    return (unsigned short)r;
}
__device__ __forceinline__ float blo(unsigned v) { return __uint_as_float(v << 16); }
__device__ __forceinline__ float bhi(unsigned v) { return __uint_as_float(v & 0xFFFF0000u); }

// ---------------- histogram of batch -> counts[64] ----------------
__global__ void k_hist(const int* __restrict__ batch, int* __restrict__ counts, int n) {
    __shared__ int hist[G_GRAPHS];
    if (threadIdx.x < G_GRAPHS) hist[threadIdx.x] = 0;
    __syncthreads();
    for (int i = blockIdx.x * blockDim.x + threadIdx.x; i < n; i += gridDim.x * blockDim.x)
        atomicAdd(&hist[batch[i]], 1);
    __syncthreads();
    if (threadIdx.x < G_GRAPHS) atomicAdd(&counts[threadIdx.x], hist[threadIdx.x]);
}

__global__ void k_gridstats(const int* __restrict__ counts, int* __restrict__ starts,
                            int* __restrict__ gridg) {
    if (threadIdx.x == 0) {
        int run = 0;
        for (int g = 0; g < G_GRAPHS; ++g) {
            starts[g] = run;
            int c = counts[g];
            run += c;
            int s = (int)sqrtf((float)c);
            while ((long long)s * s < c) ++s;
            while (s > 0 && (long long)(s - 1) * (s - 1) >= c) --s;
            gridg[g] = s;
        }
    }
}

__global__ void k_pos(const int* __restrict__ batch, const int* __restrict__ starts,
                      const int* __restrict__ gridg, float2* __restrict__ pos2) {
    int t = blockIdx.x * blockDim.x + threadIdx.x;
    if (t >= N_NODES) return;
    int b = batch[t];
    int local = t - starts[b];
    int g = max(gridg[b], 1);
    float denom = (float)max(g - 1, 1);
    int r = local / g;
    int c = local - r * g;
    pos2[t] = make_float2((float)r / denom, (float)c / denom);
}

// ---------------- weight prep: bf16 transposed [col][K] ----------------
__global__ void k_wprep(const float* __restrict__ w0, const float* __restrict__ w1,
                        const float* __restrict__ wr, unsigned short* __restrict__ t0,
                        unsigned short* __restrict__ t1, unsigned short* __restrict__ tr) {
    int t = blockIdx.x * 256 + threadIdx.x;
    if (t < 128 * K0P) {
        int c = t / K0P, k = t % K0P;
        t0[t] = (k < D0) ? f2b(w0[k * 128 + c]) : (unsigned short)0;
    } else if (t < 128 * K0P + 128 * 128) {
        int i = t - 128 * K0P;
        int c = i / 128, k = i % 128;
        t1[i] = f2b(w1[k * 128 + c]);
    } else if (t < 128 * K0P + 2 * 128 * 128) {
        int i = t - 128 * K0P - 128 * 128;
        int c = i / 128, k = i % 128;
        tr[i] = f2b(wr[k * 128 + c]);
    }
}

// ---------------- bucket histogram over dst ----------------
__global__ void k_bhist(const int* __restrict__ ei, int* __restrict__ bcount) {
    __shared__ int lh[256];
    int tid = threadIdx.x;
    lh[tid] = 0;
    __syncthreads();
    int e = (blockIdx.x * blockDim.x + tid) * 4;
    if (e < N_EDGES) {
        int4 d4 = *reinterpret_cast<const int4*>(ei + N_EDGES + e);
        atomicAdd(&lh[d4.x >> BK_SHIFT], 1);
        atomicAdd(&lh[d4.y >> BK_SHIFT], 1);
        atomicAdd(&lh[d4.z >> BK_SHIFT], 1);
        atomicAdd(&lh[d4.w >> BK_SHIFT], 1);
    }
    __syncthreads();
    if (tid < NB && lh[tid] > 0) atomicAdd(&bcount[tid], lh[tid]);
}

__global__ void k_bscan(const int* __restrict__ bcount, int* __restrict__ bstart,
                        int* __restrict__ bcursor) {
    if (threadIdx.x == 0) {
        int run = 0;
        for (int i = 0; i < NB; ++i) {
            bstart[i] = run;
            bcursor[i] = run;
            run += bcount[i];
        }
        bstart[NB] = run;
    }
}

// ---------------- tile-local counting sort -> bucket-major pairs (shfl scan) ----------------
__global__ __launch_bounds__(256) void k_bucket(const int* __restrict__ ei,
                                                int* __restrict__ bcursor,
                                                int2* __restrict__ pairs) {
    __shared__ int lh[256];
    __shared__ int lstart[256];
    __shared__ int lcur[256];
    __shared__ int gbase[256];
    __shared__ int wsum[4];
    __shared__ int2 stage[TILE_E];
    const int tid = threadIdx.x;
    const int lane = tid & 63;
    const int wid = tid >> 6;
    const int tile = blockIdx.x * TILE_E;
    const int cnt = min(TILE_E, N_EDGES - tile);
    lh[tid] = 0;
    __syncthreads();
    int sv[16], dv[16];
#pragma unroll
    for (int u = 0; u < 16; ++u) {
        int i = u * 256 + tid;
        if (i < cnt) {
            sv[u] = ei[tile + i];
            dv[u] = ei[N_EDGES + tile + i];
            atomicAdd(&lh[dv[u] >> BK_SHIFT], 1);
        } else {
            sv[u] = -1; dv[u] = -1;
        }
    }
    __syncthreads();
    int own = lh[tid];
    int incl = own;
#pragma unroll
    for (int off = 1; off < 64; off <<= 1) {
        int t = __shfl_up(incl, off, 64);
        if (lane >= off) incl += t;
    }
    if (lane == 63) wsum[wid] = incl;
    __syncthreads();
    int wo = 0;
#pragma unroll
    for (int w = 0; w < 3; ++w) if (w < wid) wo += wsum[w];
    int excl = incl - own + wo;
    lstart[tid] = excl;
    lcur[tid] = excl;
    __syncthreads();
#pragma unroll
    for (int u = 0; u < 16; ++u) {
        if (dv[u] >= 0) {
            int b = dv[u] >> BK_SHIFT;
            int slot = atomicAdd(&lcur[b], 1);
            stage[slot] = make_int2(sv[u], dv[u]);
        }
    }
    __syncthreads();
    if (tid < NB && own > 0) gbase[tid] = atomicAdd(&bcursor[tid], own);
    __syncthreads();
    for (int i = tid; i < cnt; i += 256) {
        int2 pr = stage[i];
        int b = pr.y >> BK_SHIFT;
        pairs[gbase[b] + (i - lstart[b])] = pr;
    }
}

// ---------------- per-bucket CSR finalize (shfl scan) ----------------
__global__ __launch_bounds__(256) void k_csr(const int2* __restrict__ pairs,
                                             const int* __restrict__ bstart,
                                             int* __restrict__ offs,
                                             int* __restrict__ csr_src) {
    __shared__ int ldeg[BK_NODES];
    __shared__ int lcur[BK_NODES];
    __shared__ int wsum[4];
    const int b = blockIdx.x;
    const int tid = threadIdx.x;
    const int lane = tid & 63;
    const int wid = tid >> 6;
    const int nb0 = b * BK_NODES;
    const int base = bstart[b];
    const int ecnt = bstart[b + 1] - base;
    ldeg[tid] = 0; ldeg[tid + 256] = 0;
    __syncthreads();
    for (int i = tid; i < ecnt; i += 256)
        atomicAdd(&ldeg[pairs[base + i].y - nb0], 1);
    __syncthreads();
    int v0 = ldeg[tid * 2], v1 = ldeg[tid * 2 + 1];
    int tsum = v0 + v1;
    int incl = tsum;
#pragma unroll
    for (int off = 1; off < 64; off <<= 1) {
        int t = __shfl_up(incl, off, 64);
        if (lane >= off) incl += t;
    }
    if (lane == 63) wsum[wid] = incl;
    __syncthreads();
    int wo = 0;
#pragma unroll
    for (int w = 0; w < 3; ++w) if (w < wid) wo += wsum[w];
    int excl = incl - tsum + wo;
    int o0 = base + excl;
    int o1 = o0 + v0;
    lcur[tid * 2] = o0;
    lcur[tid * 2 + 1] = o1;
    int n0 = nb0 + tid * 2, n1 = n0 + 1;
    if (n0 < N_NODES) offs[n0] = o0;
    if (n1 < N_NODES) offs[n1] = o1;
    if (b == NB - 1 && tid == 0) offs[N_NODES] = bstart[NB];
    __syncthreads();
    for (int i = tid; i < ecnt; i += 256) {
        int2 pr = pairs[base + i];
        int pos = atomicAdd(&lcur[pr.y - nb0], 1);
        csr_src[pos] = pr.x;
    }
}

// ---------------- MFMA GEMM: 64 rows x 128 cols / block ----------------
template <int K, int POS, int RES, int BF16A>
__global__ __launch_bounds__(256) void k_gemm3(
        const float* __restrict__ in, const unsigned short* __restrict__ inb,
        const float2* __restrict__ pos2,
        const float* __restrict__ posw, const float* __restrict__ posb,
        const unsigned short* __restrict__ wbT,
        const float* __restrict__ asrc, const float* __restrict__ adst,
        float* __restrict__ es, float* __restrict__ ed,
        unsigned short* __restrict__ outb,
        const unsigned short* __restrict__ wbT2, const float* __restrict__ bias2,
        unsigned short* __restrict__ outb2, int n) {
    __shared__ unsigned short At[64 * K];
    const int tid = threadIdx.x;
    const int base = blockIdx.x * 64;
    if (BF16A) {
        constexpr int KC8 = K / 8;
        for (int idx = tid; idx < 64 * KC8; idx += 256) {
            int row = idx / KC8, g = idx % KC8;
            int grow = base + row;
            short8v v = (short8v)(short)0;
            if (grow < n) v = *reinterpret_cast<const short8v*>(inb + (size_t)grow * 128 + g * 8);
            unsigned byteoff = (unsigned)((row * K + g * 8) * 2) ^ (unsigned)((row & 7) << 4);
            *reinterpret_cast<short8v*>(reinterpret_cast<char*>(At) + byteoff) = v;
        }
    } else {
        constexpr int KC4 = K / 4;
        for (int idx = tid; idx < 64 * KC4; idx += 256) {
            int row = idx / KC4, c4 = idx % KC4;
            int grow = base + row;
            float4 v = make_float4(0.f, 0.f, 0.f, 0.f);
            if (grow < n) {
                if (!POS || c4 < 32) {
                    v = reinterpret_cast<const float4*>(in)[(size_t)grow * 32 + c4];
                } else if (c4 < 36) {
                    float2 p = pos2[grow];
                    int q = c4 - 32;
                    float4 w0v = reinterpret_cast<const float4*>(posw)[q];
                    float4 w1v = reinterpret_cast<const float4*>(posw + POS_DIM)[q];
                    float4 bv  = reinterpret_cast<const float4*>(posb)[q];
                    v.x = fmaf(p.x, w0v.x, fmaf(p.y, w1v.x, bv.x));
                    v.y = fmaf(p.x, w0v.y, fmaf(p.y, w1v.y, bv.y));
                    v.z = fmaf(p.x, w0v.z, fmaf(p.y, w1v.z, bv.z));
                    v.w = fmaf(p.x, w0v.w, fmaf(p.y, w1v.w, bv.w));
                }
            }
            ushort4 b4;
            b4.x = f2b(v.x); b4.y = f2b(v.y); b4.z = f2b(v.z); b4.w = f2b(v.w);
            unsigned byteoff = (unsigned)((row * K + c4 * 4) * 2) ^ (unsigned)((row & 7) << 4);
            *reinterpret_cast<ushort4*>(reinterpret_cast<char*>(At) + byteoff) = b4;
        }
    }
    __syncthreads();

    const int wv = tid >> 6;
    const int lane = tid & 63;
    const int lrow = lane & 15;
    const int lk8 = lane >> 4;
    f32x4 acc[4][2];
    f32x4 acc2[RES ? 4 : 1][RES ? 2 : 1];
#pragma unroll
    for (int rt = 0; rt < 4; ++rt) {
#pragma unroll
        for (int ct = 0; ct < 2; ++ct) {
            acc[rt][ct] = (f32x4){0.f, 0.f, 0.f, 0.f};
            if (RES) acc2[rt][ct] = (f32x4){0.f, 0.f, 0.f, 0.f};
        }
    }
    const unsigned short* bp0 = wbT + (size_t)(wv * 32 + lrow) * K + lk8 * 8;
    const unsigned short* bp1 = bp0 + 16 * K;
    const unsigned short* cp0 = RES ? (wbT2 + (size_t)(wv * 32 + lrow) * K + lk8 * 8) : nullptr;
    const unsigned short* cp1 = RES ? cp0 + 16 * K : nullptr;

    for (int k0 = 0; k0 < K; k0 += 32) {
        short8v b0 = *reinterpret_cast<const short8v*>(bp0 + k0);
        short8v b1 = *reinterpret_cast<const short8v*>(bp1 + k0);
        short8v a[4];
#pragma unroll
        for (int rt = 0; rt < 4; ++rt) {
            int row = rt * 16 + lrow;
            unsigned byteoff = (unsigned)((row * K + k0 + lk8 * 8) * 2) ^ (unsigned)((row & 7) << 4);
            a[rt] = *reinterpret_cast<const short8v*>(reinterpret_cast<const char*>(At) + byteoff);
        }
#pragma unroll
        for (int rt = 0; rt < 4; ++rt) {
            acc[rt][0] = __builtin_amdgcn_mfma_f32_16x16x32_bf16(a[rt], b0, acc[rt][0], 0, 0, 0);
            acc[rt][1] = __builtin_amdgcn_mfma_f32_16x16x32_bf16(a[rt], b1, acc[rt][1], 0, 0, 0);
        }
        if (RES) {
            short8v c0 = *reinterpret_cast<const short8v*>(cp0 + k0);
            short8v c1 = *reinterpret_cast<const short8v*>(cp1 + k0);
#pragma unroll
            for (int rt = 0; rt < 4; ++rt) {
                acc2[rt][0] = __builtin_amdgcn_mfma_f32_16x16x32_bf16(a[rt], c0, acc2[rt][0], 0, 0, 0);
                acc2[rt][1] = __builtin_amdgcn_mfma_f32_16x16x32_bf16(a[rt], c1, acc2[rt][1], 0, 0, 0);
            }
        }
    }

    float av0 = asrc[wv * 32 + lrow], av1 = asrc[wv * 32 + 16 + lrow];
    float dv0 = adst[wv * 32 + lrow], dv1 = adst[wv * 32 + 16 + lrow];
    float bb0 = 0.f, bb1 = 0.f;
    if (RES) { bb0 = bias2[wv * 32 + lrow]; bb1 = bias2[wv * 32 + 16 + lrow]; }
#pragma unroll
    for (int rt = 0; rt < 4; ++rt) {
#pragma unroll
        for (int r = 0; r < 4; ++r) {
            int row = rt * 16 + lk8 * 4 + r;
            int grow = base + row;
            bool live = (grow < n);
            float v0 = acc[rt][0][r], v1 = acc[rt][1][r];
            if (live) {
                outb[(size_t)grow * 128 + wv * 32 + lrow] = f2b(v0);
                outb[(size_t)grow * 128 + wv * 32 + 16 + lrow] = f2b(v1);
                if (RES) {
                    outb2[(size_t)grow * 128 + wv * 32 + lrow] = f2b(acc2[rt][0][r] + bb0);
                    outb2[(size_t)grow * 128 + wv * 32 + 16 + lrow] = f2b(acc2[rt][1][r] + bb1);
                }
            }
            float ps = v0 * av0 + v1 * av1;
            float pd = v0 * dv0 + v1 * dv1;
            ps += __shfl_xor(ps, 1); pd += __shfl_xor(pd, 1);
            ps += __shfl_xor(ps, 2); pd += __shfl_xor(pd, 2);
            ps += __shfl_xor(ps, 4); pd += __shfl_xor(pd, 4);
            ps += __shfl_xor(ps, 8); pd += __shfl_xor(pd, 8);
            if (lrow == 0 && live) {
                es[grow * 4 + wv] = ps;
                ed[grow * 4 + wv] = pd;
            }
        }
    }
}

// ---------------- CSR aggregation (round-10 proven form): 1 node / wave ----------------
__global__ void k_aggb(const int* __restrict__ csr_src, const int* __restrict__ offs,
                       const float* __restrict__ es, const float* __restrict__ ed,
                       const unsigned* __restrict__ hb32, const float* __restrict__ bias,
                       float* __restrict__ out) {
    int node = blockIdx.x * 4 + (threadIdx.x >> 6);
    if (node >= N_NODES) return;
    int lane = threadIdx.x & 63;
    int hd = lane >> 4;
    float edv = ed[node * 4 + hd];
    int rs = offs[node], re_ = offs[node + 1];
    float ax[4] = {0.f, 0.f, 0.f, 0.f};
    float ay[4] = {0.f, 0.f, 0.f, 0.f};
    float ds[4] = {0.f, 0.f, 0.f, 0.f};
    int j = rs;
    for (; j + 8 <= re_; j += 8) {
        int s[8];
        float e[8];
        unsigned q[8];
#pragma unroll
        for (int u = 0; u < 8; ++u) s[u] = csr_src[j + u];
#pragma unroll
        for (int u = 0; u < 8; ++u) e[u] = es[s[u] * 4 + hd];
#pragma unroll
        for (int u = 0; u < 8; ++u) q[u] = hb32[(size_t)s[u] * 64 + lane];
#pragma unroll
        for (int u = 0; u < 8; ++u) {
            float a = e[u] + edv;
            a = (a > 0.f) ? a : LRELU_SLOPE * a;
            float x = __expf(a);
            ax[u & 3] = fmaf(x, blo(q[u]), ax[u & 3]);
            ay[u & 3] = fmaf(x, bhi(q[u]), ay[u & 3]);
            ds[u & 3] += x;
        }
    }
    for (; j < re_; ++j) {
        int s = csr_src[j];
        float a = es[s * 4 + hd] + edv;
        a = (a > 0.f) ? a : LRELU_SLOPE * a;
        float x = __expf(a);
        unsigned hv = hb32[(size_t)s * 64 + lane];
        ax[0] = fmaf(x, blo(hv), ax[0]);
        ay[0] = fmaf(x, bhi(hv), ay[0]);
        ds[0] += x;
    }
    {   // self loop
        float a = es[node * 4 + hd] + edv;
        a = (a > 0.f) ? a : LRELU_SLOPE * a;
        float x = __expf(a);
        unsigned hv = hb32[(size_t)node * 64 + lane];
        ax[0] = fmaf(x, blo(hv), ax[0]);
        ay[0] = fmaf(x, bhi(hv), ay[0]);
        ds[0] += x;
    }
    float inv = 1.f / (ds[0] + ds[1] + ds[2] + ds[3]);
    float2 o;
    o.x = fmaf(ax[0] + ax[1] + ax[2] + ax[3], inv, bias[lane * 2]);
    o.y = fmaf(ay[0] + ay[1] + ay[2] + ay[3], inv, bias[lane * 2 + 1]);
    reinterpret_cast<float2*>(out)[(size_t)node * 64 + lane] = o;
}

// ---------------- div loss + BN + ELU; LAYER0 -> bf16 h0; LAYER1 -> +res, pool, no store --
template <int LAYER>
__global__ __launch_bounds__(256) void k_divbn(
        const float* __restrict__ hin, const unsigned* __restrict__ rbuf16,
        const float* __restrict__ proj, const float* __restrict__ gamma,
        const float* __restrict__ beta, const float* __restrict__ mean,
        const float* __restrict__ var, float* __restrict__ Msum,
        unsigned* __restrict__ outb16,
        const int* __restrict__ batch, float* __restrict__ emb) {
    __shared__ float sm[6];
    const int tid = threadIdx.x;
    if (tid < 6) sm[tid] = 0.f;
    __syncthreads();
    const int lane = tid & 63;
    const int wid = tid >> 6;
    const int wave_id = blockIdx.x * 4 + wid;
    const int CH = (N_NODES + 4095) / 4096;
    const int start = wave_id * CH;
    const int end = min(start + CH, N_NODES);
    float2 pj = reinterpret_cast<const float2*>(proj)[lane];
    float2 g2 = reinterpret_cast<const float2*>(gamma)[lane];
    float2 b2 = reinterpret_cast<const float2*>(beta)[lane];
    float2 m2 = reinterpret_cast<const float2*>(mean)[lane];
    float2 v2 = reinterpret_cast<const float2*>(var)[lane];
    float scx = g2.x * rsqrtf(v2.x + BN_EPS);
    float scy = g2.y * rsqrtf(v2.y + BN_EPS);
    float accA = 0.f, accB = 0.f, accC = 0.f;
    float ex = 0.f, ey = 0.f;
    int curg = -1;
    for (int node = start; node < end; ++node) {
        float2 hv = reinterpret_cast<const float2*>(hin)[(size_t)node * 64 + lane];
        float px = hv.x * pj.x, py = hv.y * pj.y;
        float nn = px * px + py * py;
        nn += __shfl_xor(nn, 1); nn += __shfl_xor(nn, 2);
        nn += __shfl_xor(nn, 4); nn += __shfl_xor(nn, 8);
        float tx = __shfl_xor(px, 16), ty = __shfl_xor(py, 16);
        float d16 = px * tx + py * ty;
        tx = __shfl_xor(px, 32); ty = __shfl_xor(py, 32);
        float d32 = px * tx + py * ty;
        tx = __shfl_xor(px, 48); ty = __shfl_xor(py, 48);
        float d48 = px * tx + py * ty;
        d16 += __shfl_xor(d16, 1); d16 += __shfl_xor(d16, 2);
        d16 += __shfl_xor(d16, 4); d16 += __shfl_xor(d16, 8);
        d32 += __shfl_xor(d32, 1); d32 += __shfl_xor(d32, 2);
        d32 += __shfl_xor(d32, 4); d32 += __shfl_xor(d32, 8);
        d48 += __shfl_xor(d48, 1); d48 += __shfl_xor(d48, 2);
        d48 += __shfl_xor(d48, 4); d48 += __shfl_xor(d48, 8);
        float n_own = fmaxf(sqrtf(nn), 1e-8f);
        float n16 = fmaxf(sqrtf(__shfl_xor(nn, 16)), 1e-8f);
        float n32 = fmaxf(sqrtf(__shfl_xor(nn, 32)), 1e-8f);
        float n48 = fmaxf(sqrtf(__shfl_xor(nn, 48)), 1e-8f);
        accA += d16 / (n_own * n16);
        accB += d32 / (n_own * n32);
        accC += d48 / (n_own * n48);
        float yx = (hv.x - m2.x) * scx + b2.x;
        float yy = (hv.y - m2.y) * scy + b2.y;
        yx = (yx > 0.f) ? yx : (__expf(yx) - 1.f);
        yy = (yy > 0.f) ? yy : (__expf(yy) - 1.f);
        if (LAYER == 1) {
            unsigned rb = rbuf16[(size_t)node * 64 + lane];
            yx += blo(rb);
            yy += bhi(rb);
            int g = batch[node];
            if (g != curg) {
                if (curg >= 0) {
                    unsafeAtomicAdd(&emb[curg * 128 + lane * 2], ex);
                    unsafeAtomicAdd(&emb[curg * 128 + lane * 2 + 1], ey);
                }
                curg = g; ex = 0.f; ey = 0.f;
            }
            ex += yx; ey += yy;
        } else {
            outb16[(size_t)node * 64 + lane] = (unsigned)f2b(yx) | ((unsigned)f2b(yy) << 16);
        }
    }
    if (LAYER == 1 && curg >= 0) {
        unsafeAtomicAdd(&emb[curg * 128 + lane * 2], ex);
        unsafeAtomicAdd(&emb[curg * 128 + lane * 2 + 1], ey);
    }
    int g = lane >> 4;
    if ((lane & 15) == 0) {
        if (g == 0) {
            atomicAdd(&sm[0], accA);
            atomicAdd(&sm[1], accB);
            atomicAdd(&sm[2], accC);
        } else if (g == 1) {
            atomicAdd(&sm[4], accB);
            atomicAdd(&sm[3], accC);
        } else if (g == 2) {
            atomicAdd(&sm[5], accA);
        }
    }
    __syncthreads();
    if (tid < 6) unsafeAtomicAdd(&Msum[tid], sm[tid]);
}

// ---------------- final: emb normalize, task head, div scalar ----------------
__global__ void k_final(const float* __restrict__ emb_ws, const int* __restrict__ counts,
                        const float* __restrict__ task_w, const float* __restrict__ task_b,
                        const float* __restrict__ Msum, float* __restrict__ out) {
    __shared__ float e_lds[G_GRAPHS * 128];
    __shared__ float cnt[G_GRAPHS];
    int tid = threadIdx.x;
    if (tid < G_GRAPHS) cnt[tid] = fmaxf((float)counts[tid], 1.f);
    __syncthreads();
    for (int i = tid; i < G_GRAPHS * 128; i += 256) {
        float v = emb_ws[i] / cnt[i >> 7];
        e_lds[i] = v;
        out[641 + i] = v;
    }
    __syncthreads();
    for (int p = tid; p < G_GRAPHS * OUT_DIM; p += 256) {
        int g = p / OUT_DIM, o = p % OUT_DIM;
        float acc = task_b[o];
#pragma unroll 8
        for (int k = 0; k < 128; ++k) acc = fmaf(e_lds[g * 128 + k], task_w[k * OUT_DIM + o], acc);
        out[p] = acc;
    }
    if (tid == 0) {
        float div = 0.f;
        for (int l = 0; l < 2; ++l) {
            float s = 0.f;
            for (int p = 0; p < 6; ++p) {
                float m = Msum[l * 6 + p] / (float)N_NODES;
                s = fmaf(m, m, s);
            }
            div += s / 6.f;
        }
        out[G_GRAPHS * OUT_DIM] = DIV_W * div;
    }
}

extern "C" void kernel_launch(void* const* d_in, const int* in_sizes, int n_in,
                              void* d_out, int out_size, void* d_ws, size_t ws_size,
                              hipStream_t stream) {
    const float* x      = (const float*)d_in[0];
    const int*   ei     = (const int*)d_in[1];
    const int*   batch  = (const int*)d_in[2];
    const float* pos_w  = (const float*)d_in[3];
    const float* pos_b  = (const float*)d_in[4];
    const float* w0     = (const float*)d_in[5];
    const float* asrc0  = (const float*)d_in[6];
    const float* adst0  = (const float*)d_in[7];
    const float* b0     = (const float*)d_in[8];
    const float* w1     = (const float*)d_in[9];
    const float* asrc1  = (const float*)d_in[10];
    const float* adst1  = (const float*)d_in[11];
    const float* b1     = (const float*)d_in[12];
    const float* bn_gamma = (const float*)d_in[13];
    const float* bn_beta  = (const float*)d_in[14];
    const float* bn_mean  = (const float*)d_in[15];
    const float* bn_var   = (const float*)d_in[16];
    const float* proj   = (const float*)d_in[17];
    const float* res_w  = (const float*)d_in[18];
    const float* res_b  = (const float*)d_in[19];
    const float* task_w = (const float*)d_in[20];
    const float* task_b = (const float*)d_in[21];
    float* out = (float*)d_out;

    // workspace layout
    unsigned short* wbT0 = (unsigned short*)d_ws;
    unsigned short* wbT1 = wbT0 + 128 * K0P;
    unsigned short* wbTr = wbT1 + 128 * 128;
    unsigned short* hb   = wbTr + 128 * 128;                   // N*128 bf16 (gemm out h)
    unsigned short* hb0  = hb + (size_t)N_NODES * 128;         // N*128 bf16 (layer0 act)
    unsigned short* bbuf = hb0 + (size_t)N_NODES * 128;        // N*128 bf16 (res proj)
    float* p = (float*)(bbuf + (size_t)N_NODES * 128);
    float* abuf = p; p += (size_t)N_NODES * D1;                // agg out (f32)
    float* es   = p; p += (size_t)N_NODES * 4;
    float* ed   = p; p += (size_t)N_NODES * 4;
    float2* pos2 = (float2*)p; p += (size_t)N_NODES * 2;
    float* emb  = p; p += G_GRAPHS * 128;
    float* Msum = p; p += 16;
    int* counts = (int*)p;
    int* starts  = counts + G_GRAPHS;
    int* gridg   = starts + G_GRAPHS;
    int* bcount  = gridg + G_GRAPHS;
    int* bstart  = bcount + NB;
    int* bcursor = bstart + NB + 1;
    int* offs    = bcursor + NB;
    int* csr_src = (int*)(((uintptr_t)(offs + N_NODES + 1) + 15) & ~(uintptr_t)15);
    int2* pairs  = (int2*)(csr_src + N_EDGES + 8);

    const int B = 256;

    hipMemsetAsync(counts, 0, G_GRAPHS * sizeof(int), stream);
    hipMemsetAsync(Msum, 0, 12 * sizeof(float), stream);
    hipMemsetAsync(bcount, 0, NB * sizeof(int), stream);
    hipMemsetAsync(emb, 0, G_GRAPHS * 128 * sizeof(float), stream);
    hipMemsetAsync(csr_src + N_EDGES, 0, 8 * sizeof(int), stream);
    k_hist<<<256, B, 0, stream>>>(batch, counts, N_NODES);
    k_gridstats<<<1, 64, 0, stream>>>(counts, starts, gridg);
    k_pos<<<(N_NODES + B - 1) / B, B, 0, stream>>>(batch, starts, gridg, pos2);
    k_wprep<<<(128 * K0P + 2 * 128 * 128 + 255) / 256, 256, 0, stream>>>(
        w0, w1, res_w, wbT0, wbT1, wbTr);

    // CSR build: bucketed two-pass sort
    k_bhist<<<(N_EDGES / 4 + B - 1) / B, B, 0, stream>>>(ei, bcount);
    k_bscan<<<1, 64, 0, stream>>>(bcount, bstart, bcursor);
    k_bucket<<<NTILES, B, 0, stream>>>(ei, bcursor, pairs);
    k_csr<<<NB, B, 0, stream>>>(pairs, bstart, offs, csr_src);

    const int GB = (N_NODES + 63) / 64;
    const int AB = (N_NODES + 3) / 4;

    // ---- layer 0 ----
    k_gemm3<K0P, 1, 0, 0><<<GB, 256, 0, stream>>>(
        x, nullptr, pos2, pos_w, pos_b, wbT0, asrc0, adst0, es, ed, hb,
        nullptr, nullptr, nullptr, N_NODES);
    k_aggb<<<AB, B, 0, stream>>>(csr_src, offs, es, ed, (const unsigned*)hb, b0, abuf);
    k_divbn<0><<<1024, B, 0, stream>>>(
        abuf, nullptr, proj, bn_gamma, bn_beta, bn_mean, bn_var, Msum,
        (unsigned*)hb0, nullptr, nullptr);

    // ---- layer 1 ----
    k_gemm3<D1, 0, 1, 1><<<GB, 256, 0, stream>>>(
        nullptr, hb0, nullptr, nullptr, nullptr, wbT1, asrc1, adst1, es, ed, hb,
        wbTr, res_b, bbuf, N_NODES);
    k_aggb<<<AB, B, 0, stream>>>(csr_src, offs, es, ed, (const unsigned*)hb, b1, abuf);
    k_divbn<1><<<1024, B, 0, stream>>>(
        abuf, (const unsigned*)bbuf, proj + HEADS * HID, bn_gamma + D1, bn_beta + D1,
        bn_mean + D1, bn_var + D1, Msum + 6, nullptr, batch, emb);

    // heads
    k_final<<<1, B, 0, stream>>>(emb, counts, task_w, task_b, Msum, out);
}

// Round 13
// 457.226 us; speedup vs baseline: 1.8896x; 1.0979x over previous
//
#include <hip/hip_runtime.h>
#include <hip/hip_bf16.h>

#define N_NODES 100000
#define N_EDGES 1600000
#define G_GRAPHS 64
#define D_IN 128
#define POS_DIM 16
#define HID 32
#define HEADS 4
#define OUT_DIM 10
#define D0 144
#define D1 128
#define LRELU_SLOPE 0.2f
#define BN_EPS 1e-5f
#define DIV_W 0.1f

#define BK_SHIFT 9
#define BK_NODES 512
#define NB 196
#define TILE_E 4096
#define NTILES ((N_EDGES + TILE_E - 1) / TILE_E)

#define K0P 160

typedef __attribute__((ext_vector_type(8))) short short8v;
typedef __attribute__((ext_vector_type(4))) float f32x4;

__device__ __forceinline__ unsigned short f2b(float f) {
    unsigned u = __float_as_uint(f);
    unsigned r = (u + 0x7FFFu + ((u >> 16) & 1u)) >> 16;
    return (unsigned short)r;
}
__device__ __forceinline__ float blo(unsigned v) { return __uint_as_float(v << 16); }
__device__ __forceinline__ float bhi(unsigned v) { return __uint_as_float(v & 0xFFFF0000u); }

// ---------------- histogram of batch -> counts[64] ----------------
__global__ void k_hist(const int* __restrict__ batch, int* __restrict__ counts, int n) {
    __shared__ int hist[G_GRAPHS];
    if (threadIdx.x < G_GRAPHS) hist[threadIdx.x] = 0;
    __syncthreads();
    for (int i = blockIdx.x * blockDim.x + threadIdx.x; i < n; i += gridDim.x * blockDim.x)
        atomicAdd(&hist[batch[i]], 1);
    __syncthreads();
    if (threadIdx.x < G_GRAPHS) atomicAdd(&counts[threadIdx.x], hist[threadIdx.x]);
}

__global__ void k_gridstats(const int* __restrict__ counts, int* __restrict__ starts,
                            int* __restrict__ gridg) {
    if (threadIdx.x == 0) {
        int run = 0;
        for (int g = 0; g < G_GRAPHS; ++g) {
            starts[g] = run;
            int c = counts[g];
            run += c;
            int s = (int)sqrtf((float)c);
            while ((long long)s * s < c) ++s;
            while (s > 0 && (long long)(s - 1) * (s - 1) >= c) --s;
            gridg[g] = s;
        }
    }
}

__global__ void k_pos(const int* __restrict__ batch, const int* __restrict__ starts,
                      const int* __restrict__ gridg, float2* __restrict__ pos2) {
    int t = blockIdx.x * blockDim.x + threadIdx.x;
    if (t >= N_NODES) return;
    int b = batch[t];
    int local = t - starts[b];
    int g = max(gridg[b], 1);
    float denom = (float)max(g - 1, 1);
    int r = local / g;
    int c = local - r * g;
    pos2[t] = make_float2((float)r / denom, (float)c / denom);
}

// ---------------- weight prep: bf16 transposed [col][K] ----------------
__global__ void k_wprep(const float* __restrict__ w0, const float* __restrict__ w1,
                        const float* __restrict__ wr, unsigned short* __restrict__ t0,
                        unsigned short* __restrict__ t1, unsigned short* __restrict__ tr) {
    int t = blockIdx.x * 256 + threadIdx.x;
    if (t < 128 * K0P) {
        int c = t / K0P, k = t % K0P;
        t0[t] = (k < D0) ? f2b(w0[k * 128 + c]) : (unsigned short)0;
    } else if (t < 128 * K0P + 128 * 128) {
        int i = t - 128 * K0P;
        int c = i / 128, k = i % 128;
        t1[i] = f2b(w1[k * 128 + c]);
    } else if (t < 128 * K0P + 2 * 128 * 128) {
        int i = t - 128 * K0P - 128 * 128;
        int c = i / 128, k = i % 128;
        tr[i] = f2b(wr[k * 128 + c]);
    }
}

// ---------------- bucket histogram over dst (x8 unrolled) ----------------
__global__ void k_bhist(const int* __restrict__ ei, int* __restrict__ bcount) {
    __shared__ int lh[256];
    int tid = threadIdx.x;
    lh[tid] = 0;
    __syncthreads();
    int e = (blockIdx.x * blockDim.x + tid) * 8;
    if (e < N_EDGES) {
        int4 d4 = *reinterpret_cast<const int4*>(ei + N_EDGES + e);
        int4 d5 = *reinterpret_cast<const int4*>(ei + N_EDGES + e + 4);
        atomicAdd(&lh[d4.x >> BK_SHIFT], 1);
        atomicAdd(&lh[d4.y >> BK_SHIFT], 1);
        atomicAdd(&lh[d4.z >> BK_SHIFT], 1);
        atomicAdd(&lh[d4.w >> BK_SHIFT], 1);
        atomicAdd(&lh[d5.x >> BK_SHIFT], 1);
        atomicAdd(&lh[d5.y >> BK_SHIFT], 1);
        atomicAdd(&lh[d5.z >> BK_SHIFT], 1);
        atomicAdd(&lh[d5.w >> BK_SHIFT], 1);
    }
    __syncthreads();
    if (tid < NB && lh[tid] > 0) atomicAdd(&bcount[tid], lh[tid]);
}

__global__ void k_bscan(const int* __restrict__ bcount, int* __restrict__ bstart,
                        int* __restrict__ bcursor) {
    if (threadIdx.x == 0) {
        int run = 0;
        for (int i = 0; i < NB; ++i) {
            bstart[i] = run;
            bcursor[i] = run;
            run += bcount[i];
        }
        bstart[NB] = run;
    }
}

// ---------------- tile-local counting sort -> bucket-major pairs (shfl scan) ----------------
__global__ __launch_bounds__(256) void k_bucket(const int* __restrict__ ei,
                                                int* __restrict__ bcursor,
                                                int2* __restrict__ pairs) {
    __shared__ int lh[256];
    __shared__ int lstart[256];
    __shared__ int lcur[256];
    __shared__ int gbase[256];
    __shared__ int wsum[4];
    __shared__ int2 stage[TILE_E];
    const int tid = threadIdx.x;
    const int lane = tid & 63;
    const int wid = tid >> 6;
    const int tile = blockIdx.x * TILE_E;
    const int cnt = min(TILE_E, N_EDGES - tile);
    lh[tid] = 0;
    __syncthreads();
    int sv[16], dv[16];
#pragma unroll
    for (int u = 0; u < 16; ++u) {
        int i = u * 256 + tid;
        if (i < cnt) {
            sv[u] = ei[tile + i];
            dv[u] = ei[N_EDGES + tile + i];
            atomicAdd(&lh[dv[u] >> BK_SHIFT], 1);
        } else {
            sv[u] = -1; dv[u] = -1;
        }
    }
    __syncthreads();
    int own = lh[tid];
    int incl = own;
#pragma unroll
    for (int off = 1; off < 64; off <<= 1) {
        int t = __shfl_up(incl, off, 64);
        if (lane >= off) incl += t;
    }
    if (lane == 63) wsum[wid] = incl;
    __syncthreads();
    int wo = 0;
#pragma unroll
    for (int w = 0; w < 3; ++w) if (w < wid) wo += wsum[w];
    int excl = incl - own + wo;
    lstart[tid] = excl;
    lcur[tid] = excl;
    __syncthreads();
#pragma unroll
    for (int u = 0; u < 16; ++u) {
        if (dv[u] >= 0) {
            int b = dv[u] >> BK_SHIFT;
            int slot = atomicAdd(&lcur[b], 1);
            stage[slot] = make_int2(sv[u], dv[u]);
        }
    }
    __syncthreads();
    if (tid < NB && own > 0) gbase[tid] = atomicAdd(&bcursor[tid], own);
    __syncthreads();
    for (int i = tid; i < cnt; i += 256) {
        int2 pr = stage[i];
        int b = pr.y >> BK_SHIFT;
        pairs[gbase[b] + (i - lstart[b])] = pr;
    }
}

// ---------------- per-bucket CSR finalize (shfl scan) ----------------
__global__ __launch_bounds__(256) void k_csr(const int2* __restrict__ pairs,
                                             const int* __restrict__ bstart,
                                             int* __restrict__ offs,
                                             int* __restrict__ csr_src) {
    __shared__ int ldeg[BK_NODES];
    __shared__ int lcur[BK_NODES];
    __shared__ int wsum[4];
    const int b = blockIdx.x;
    const int tid = threadIdx.x;
    const int lane = tid & 63;
    const int wid = tid >> 6;
    const int nb0 = b * BK_NODES;
    const int base = bstart[b];
    const int ecnt = bstart[b + 1] - base;
    ldeg[tid] = 0; ldeg[tid + 256] = 0;
    __syncthreads();
    for (int i = tid; i < ecnt; i += 256)
        atomicAdd(&ldeg[pairs[base + i].y - nb0], 1);
    __syncthreads();
    int v0 = ldeg[tid * 2], v1 = ldeg[tid * 2 + 1];
    int tsum = v0 + v1;
    int incl = tsum;
#pragma unroll
    for (int off = 1; off < 64; off <<= 1) {
        int t = __shfl_up(incl, off, 64);
        if (lane >= off) incl += t;
    }
    if (lane == 63) wsum[wid] = incl;
    __syncthreads();
    int wo = 0;
#pragma unroll
    for (int w = 0; w < 3; ++w) if (w < wid) wo += wsum[w];
    int excl = incl - tsum + wo;
    int o0 = base + excl;
    int o1 = o0 + v0;
    lcur[tid * 2] = o0;
    lcur[tid * 2 + 1] = o1;
    int n0 = nb0 + tid * 2, n1 = n0 + 1;
    if (n0 < N_NODES) offs[n0] = o0;
    if (n1 < N_NODES) offs[n1] = o1;
    if (b == NB - 1 && tid == 0) offs[N_NODES] = bstart[NB];
    __syncthreads();
    for (int i = tid; i < ecnt; i += 256) {
        int2 pr = pairs[base + i];
        int pos = atomicAdd(&lcur[pr.y - nb0], 1);
        csr_src[pos] = pr.x;
    }
}

// ---------------- MFMA GEMM: 64 rows x 128 cols / block ----------------
template <int K, int POS, int RES, int BF16A>
__global__ __launch_bounds__(256) void k_gemm3(
        const float* __restrict__ in, const unsigned short* __restrict__ inb,
        const float2* __restrict__ pos2,
        const float* __restrict__ posw, const float* __restrict__ posb,
        const unsigned short* __restrict__ wbT,
        const float* __restrict__ asrc, const float* __restrict__ adst,
        float* __restrict__ es, float* __restrict__ ed,
        unsigned short* __restrict__ outb,
        const unsigned short* __restrict__ wbT2, const float* __restrict__ bias2,
        unsigned short* __restrict__ outb2, int n) {
    __shared__ unsigned short At[64 * K];
    const int tid = threadIdx.x;
    const int base = blockIdx.x * 64;
    if (BF16A) {
        constexpr int KC8 = K / 8;
        for (int idx = tid; idx < 64 * KC8; idx += 256) {
            int row = idx / KC8, g = idx % KC8;
            int grow = base + row;
            short8v v = (short8v)(short)0;
            if (grow < n) v = *reinterpret_cast<const short8v*>(inb + (size_t)grow * 128 + g * 8);
            unsigned byteoff = (unsigned)((row * K + g * 8) * 2) ^ (unsigned)((row & 7) << 4);
            *reinterpret_cast<short8v*>(reinterpret_cast<char*>(At) + byteoff) = v;
        }
    } else {
        constexpr int KC4 = K / 4;
        for (int idx = tid; idx < 64 * KC4; idx += 256) {
            int row = idx / KC4, c4 = idx % KC4;
            int grow = base + row;
            float4 v = make_float4(0.f, 0.f, 0.f, 0.f);
            if (grow < n) {
                if (!POS || c4 < 32) {
                    v = reinterpret_cast<const float4*>(in)[(size_t)grow * 32 + c4];
                } else if (c4 < 36) {
                    float2 p = pos2[grow];
                    int q = c4 - 32;
                    float4 w0v = reinterpret_cast<const float4*>(posw)[q];
                    float4 w1v = reinterpret_cast<const float4*>(posw + POS_DIM)[q];
                    float4 bv  = reinterpret_cast<const float4*>(posb)[q];
                    v.x = fmaf(p.x, w0v.x, fmaf(p.y, w1v.x, bv.x));
                    v.y = fmaf(p.x, w0v.y, fmaf(p.y, w1v.y, bv.y));
                    v.z = fmaf(p.x, w0v.z, fmaf(p.y, w1v.z, bv.z));
                    v.w = fmaf(p.x, w0v.w, fmaf(p.y, w1v.w, bv.w));
                }
            }
            ushort4 b4;
            b4.x = f2b(v.x); b4.y = f2b(v.y); b4.z = f2b(v.z); b4.w = f2b(v.w);
            unsigned byteoff = (unsigned)((row * K + c4 * 4) * 2) ^ (unsigned)((row & 7) << 4);
            *reinterpret_cast<ushort4*>(reinterpret_cast<char*>(At) + byteoff) = b4;
        }
    }
    __syncthreads();

    const int wv = tid >> 6;
    const int lane = tid & 63;
    const int lrow = lane & 15;
    const int lk8 = lane >> 4;
    f32x4 acc[4][2];
    f32x4 acc2[RES ? 4 : 1][RES ? 2 : 1];
#pragma unroll
    for (int rt = 0; rt < 4; ++rt) {
#pragma unroll
        for (int ct = 0; ct < 2; ++ct) {
            acc[rt][ct] = (f32x4){0.f, 0.f, 0.f, 0.f};
            if (RES) acc2[rt][ct] = (f32x4){0.f, 0.f, 0.f, 0.f};
        }
    }
    const unsigned short* bp0 = wbT + (size_t)(wv * 32 + lrow) * K + lk8 * 8;
    const unsigned short* bp1 = bp0 + 16 * K;
    const unsigned short* cp0 = RES ? (wbT2 + (size_t)(wv * 32 + lrow) * K + lk8 * 8) : nullptr;
    const unsigned short* cp1 = RES ? cp0 + 16 * K : nullptr;

    for (int k0 = 0; k0 < K; k0 += 32) {
        short8v b0 = *reinterpret_cast<const short8v*>(bp0 + k0);
        short8v b1 = *reinterpret_cast<const short8v*>(bp1 + k0);
        short8v a[4];
#pragma unroll
        for (int rt = 0; rt < 4; ++rt) {
            int row = rt * 16 + lrow;
            unsigned byteoff = (unsigned)((row * K + k0 + lk8 * 8) * 2) ^ (unsigned)((row & 7) << 4);
            a[rt] = *reinterpret_cast<const short8v*>(reinterpret_cast<const char*>(At) + byteoff);
        }
#pragma unroll
        for (int rt = 0; rt < 4; ++rt) {
            acc[rt][0] = __builtin_amdgcn_mfma_f32_16x16x32_bf16(a[rt], b0, acc[rt][0], 0, 0, 0);
            acc[rt][1] = __builtin_amdgcn_mfma_f32_16x16x32_bf16(a[rt], b1, acc[rt][1], 0, 0, 0);
        }
        if (RES) {
            short8v c0 = *reinterpret_cast<const short8v*>(cp0 + k0);
            short8v c1 = *reinterpret_cast<const short8v*>(cp1 + k0);
#pragma unroll
            for (int rt = 0; rt < 4; ++rt) {
                acc2[rt][0] = __builtin_amdgcn_mfma_f32_16x16x32_bf16(a[rt], c0, acc2[rt][0], 0, 0, 0);
                acc2[rt][1] = __builtin_amdgcn_mfma_f32_16x16x32_bf16(a[rt], c1, acc2[rt][1], 0, 0, 0);
            }
        }
    }

    float av0 = asrc[wv * 32 + lrow], av1 = asrc[wv * 32 + 16 + lrow];
    float dv0 = adst[wv * 32 + lrow], dv1 = adst[wv * 32 + 16 + lrow];
    float bb0 = 0.f, bb1 = 0.f;
    if (RES) { bb0 = bias2[wv * 32 + lrow]; bb1 = bias2[wv * 32 + 16 + lrow]; }
#pragma unroll
    for (int rt = 0; rt < 4; ++rt) {
#pragma unroll
        for (int r = 0; r < 4; ++r) {
            int row = rt * 16 + lk8 * 4 + r;
            int grow = base + row;
            bool live = (grow < n);
            float v0 = acc[rt][0][r], v1 = acc[rt][1][r];
            if (live) {
                outb[(size_t)grow * 128 + wv * 32 + lrow] = f2b(v0);
                outb[(size_t)grow * 128 + wv * 32 + 16 + lrow] = f2b(v1);
                if (RES) {
                    outb2[(size_t)grow * 128 + wv * 32 + lrow] = f2b(acc2[rt][0][r] + bb0);
                    outb2[(size_t)grow * 128 + wv * 32 + 16 + lrow] = f2b(acc2[rt][1][r] + bb1);
                }
            }
            float ps = v0 * av0 + v1 * av1;
            float pd = v0 * dv0 + v1 * dv1;
            ps += __shfl_xor(ps, 1); pd += __shfl_xor(pd, 1);
            ps += __shfl_xor(ps, 2); pd += __shfl_xor(pd, 2);
            ps += __shfl_xor(ps, 4); pd += __shfl_xor(pd, 4);
            ps += __shfl_xor(ps, 8); pd += __shfl_xor(pd, 8);
            if (lrow == 0 && live) {
                es[grow * 4 + wv] = ps;
                ed[grow * 4 + wv] = pd;
            }
        }
    }
}

// ---------------- CSR aggregation: 1 node / wave, masked aligned int4 csr loads ----------------
__global__ void k_aggb(const int* __restrict__ csr_src, const int* __restrict__ offs,
                       const float* __restrict__ es, const float* __restrict__ ed,
                       const unsigned* __restrict__ hb32, const float* __restrict__ bias,
                       float* __restrict__ out) {
    int node = blockIdx.x * 4 + (threadIdx.x >> 6);
    if (node >= N_NODES) return;
    int lane = threadIdx.x & 63;
    int hd = lane >> 4;
    float edv = ed[node * 4 + hd];
    int rs = offs[node], re_ = offs[node + 1];
    float ax[4] = {0.f, 0.f, 0.f, 0.f};
    float ay[4] = {0.f, 0.f, 0.f, 0.f};
    float ds[4] = {0.f, 0.f, 0.f, 0.f};
    for (int j = rs & ~7; j < re_; j += 8) {
        int4 c0 = *reinterpret_cast<const int4*>(csr_src + j);
        int4 c1 = *reinterpret_cast<const int4*>(csr_src + j + 4);
        int s[8] = {c0.x, c0.y, c0.z, c0.w, c1.x, c1.y, c1.z, c1.w};
        float e[8];
        unsigned q[8];
#pragma unroll
        for (int u = 0; u < 8; ++u) e[u] = es[s[u] * 4 + hd];
#pragma unroll
        for (int u = 0; u < 8; ++u) q[u] = hb32[(size_t)s[u] * 64 + lane];
#pragma unroll
        for (int u = 0; u < 8; ++u) {
            int idx = j + u;
            float a = e[u] + edv;
            a = (a > 0.f) ? a : LRELU_SLOPE * a;
            float x = (idx >= rs && idx < re_) ? __expf(a) : 0.f;
            ax[u & 3] = fmaf(x, blo(q[u]), ax[u & 3]);
            ay[u & 3] = fmaf(x, bhi(q[u]), ay[u & 3]);
            ds[u & 3] += x;
        }
    }
    {   // self loop
        float a = es[node * 4 + hd] + edv;
        a = (a > 0.f) ? a : LRELU_SLOPE * a;
        float x = __expf(a);
        unsigned hv = hb32[(size_t)node * 64 + lane];
        ax[0] = fmaf(x, blo(hv), ax[0]);
        ay[0] = fmaf(x, bhi(hv), ay[0]);
        ds[0] += x;
    }
    float inv = 1.f / (ds[0] + ds[1] + ds[2] + ds[3]);
    float2 o;
    o.x = fmaf(ax[0] + ax[1] + ax[2] + ax[3], inv, bias[lane * 2]);
    o.y = fmaf(ay[0] + ay[1] + ay[2] + ay[3], inv, bias[lane * 2 + 1]);
    reinterpret_cast<float2*>(out)[(size_t)node * 64 + lane] = o;
}

// ---------------- div loss + BN + ELU; LAYER0 -> bf16 h0; LAYER1 -> +res, pool, no store --
template <int LAYER>
__global__ __launch_bounds__(256) void k_divbn(
        const float* __restrict__ hin, const unsigned* __restrict__ rbuf16,
        const float* __restrict__ proj, const float* __restrict__ gamma,
        const float* __restrict__ beta, const float* __restrict__ mean,
        const float* __restrict__ var, float* __restrict__ Msum,
        unsigned* __restrict__ outb16,
        const int* __restrict__ batch, float* __restrict__ emb) {
    __shared__ float sm[6];
    const int tid = threadIdx.x;
    if (tid < 6) sm[tid] = 0.f;
    __syncthreads();
    const int lane = tid & 63;
    const int wid = tid >> 6;
    const int wave_id = blockIdx.x * 4 + wid;
    const int CH = (N_NODES + 4095) / 4096;
    const int start = wave_id * CH;
    const int end = min(start + CH, N_NODES);
    float2 pj = reinterpret_cast<const float2*>(proj)[lane];
    float2 g2 = reinterpret_cast<const float2*>(gamma)[lane];
    float2 b2 = reinterpret_cast<const float2*>(beta)[lane];
    float2 m2 = reinterpret_cast<const float2*>(mean)[lane];
    float2 v2 = reinterpret_cast<const float2*>(var)[lane];
    float scx = g2.x * rsqrtf(v2.x + BN_EPS);
    float scy = g2.y * rsqrtf(v2.y + BN_EPS);
    float accA = 0.f, accB = 0.f, accC = 0.f;
    float ex = 0.f, ey = 0.f;
    int curg = -1;
    for (int node = start; node < end; ++node) {
        float2 hv = reinterpret_cast<const float2*>(hin)[(size_t)node * 64 + lane];
        float px = hv.x * pj.x, py = hv.y * pj.y;
        float nn = px * px + py * py;
        nn += __shfl_xor(nn, 1); nn += __shfl_xor(nn, 2);
        nn += __shfl_xor(nn, 4); nn += __shfl_xor(nn, 8);
        float tx = __shfl_xor(px, 16), ty = __shfl_xor(py, 16);
        float d16 = px * tx + py * ty;
        tx = __shfl_xor(px, 32); ty = __shfl_xor(py, 32);
        float d32 = px * tx + py * ty;
        tx = __shfl_xor(px, 48); ty = __shfl_xor(py, 48);
        float d48 = px * tx + py * ty;
        d16 += __shfl_xor(d16, 1); d16 += __shfl_xor(d16, 2);
        d16 += __shfl_xor(d16, 4); d16 += __shfl_xor(d16, 8);
        d32 += __shfl_xor(d32, 1); d32 += __shfl_xor(d32, 2);
        d32 += __shfl_xor(d32, 4); d32 += __shfl_xor(d32, 8);
        d48 += __shfl_xor(d48, 1); d48 += __shfl_xor(d48, 2);
        d48 += __shfl_xor(d48, 4); d48 += __shfl_xor(d48, 8);
        float n_own = fmaxf(sqrtf(nn), 1e-8f);
        float n16 = fmaxf(sqrtf(__shfl_xor(nn, 16)), 1e-8f);
        float n32 = fmaxf(sqrtf(__shfl_xor(nn, 32)), 1e-8f);
        float n48 = fmaxf(sqrtf(__shfl_xor(nn, 48)), 1e-8f);
        accA += d16 / (n_own * n16);
        accB += d32 / (n_own * n32);
        accC += d48 / (n_own * n48);
        float yx = (hv.x - m2.x) * scx + b2.x;
        float yy = (hv.y - m2.y) * scy + b2.y;
        yx = (yx > 0.f) ? yx : (__expf(yx) - 1.f);
        yy = (yy > 0.f) ? yy : (__expf(yy) - 1.f);
        if (LAYER == 1) {
            unsigned rb = rbuf16[(size_t)node * 64 + lane];
            yx += blo(rb);
            yy += bhi(rb);
            int g = batch[node];
            if (g != curg) {
                if (curg >= 0) {
                    unsafeAtomicAdd(&emb[curg * 128 + lane * 2], ex);
                    unsafeAtomicAdd(&emb[curg * 128 + lane * 2 + 1], ey);
                }
                curg = g; ex = 0.f; ey = 0.f;
            }
            ex += yx; ey += yy;
        } else {
            outb16[(size_t)node * 64 + lane] = (unsigned)f2b(yx) | ((unsigned)f2b(yy) << 16);
        }
    }
    if (LAYER == 1 && curg >= 0) {
        unsafeAtomicAdd(&emb[curg * 128 + lane * 2], ex);
        unsafeAtomicAdd(&emb[curg * 128 + lane * 2 + 1], ey);
    }
    int g = lane >> 4;
    if ((lane & 15) == 0) {
        if (g == 0) {
            atomicAdd(&sm[0], accA);
            atomicAdd(&sm[1], accB);
            atomicAdd(&sm[2], accC);
        } else if (g == 1) {
            atomicAdd(&sm[4], accB);
            atomicAdd(&sm[3], accC);
        } else if (g == 2) {
            atomicAdd(&sm[5], accA);
        }
    }
    __syncthreads();
    if (tid < 6) unsafeAtomicAdd(&Msum[tid], sm[tid]);
}

// ---------------- final: emb normalize, task head, div scalar ----------------
__global__ void k_final(const float* __restrict__ emb_ws, const int* __restrict__ counts,
                        const float* __restrict__ task_w, const float* __restrict__ task_b,
                        const float* __restrict__ Msum, float* __restrict__ out) {
    __shared__ float e_lds[G_GRAPHS * 128];
    __shared__ float cnt[G_GRAPHS];
    int tid = threadIdx.x;
    if (tid < G_GRAPHS) cnt[tid] = fmaxf((float)counts[tid], 1.f);
    __syncthreads();
    for (int i = tid; i < G_GRAPHS * 128; i += 256) {
        float v = emb_ws[i] / cnt[i >> 7];
        e_lds[i] = v;
        out[641 + i] = v;
    }
    __syncthreads();
    for (int p = tid; p < G_GRAPHS * OUT_DIM; p += 256) {
        int g = p / OUT_DIM, o = p % OUT_DIM;
        float acc = task_b[o];
#pragma unroll 8
        for (int k = 0; k < 128; ++k) acc = fmaf(e_lds[g * 128 + k], task_w[k * OUT_DIM + o], acc);
        out[p] = acc;
    }
    if (tid == 0) {
        float div = 0.f;
        for (int l = 0; l < 2; ++l) {
            float s = 0.f;
            for (int p = 0; p < 6; ++p) {
                float m = Msum[l * 6 + p] / (float)N_NODES;
                s = fmaf(m, m, s);
            }
            div += s / 6.f;
        }
        out[G_GRAPHS * OUT_DIM] = DIV_W * div;
    }
}

extern "C" void kernel_launch(void* const* d_in, const int* in_sizes, int n_in,
                              void* d_out, int out_size, void* d_ws, size_t ws_size,
                              hipStream_t stream) {
    const float* x      = (const float*)d_in[0];
    const int*   ei     = (const int*)d_in[1];
    const int*   batch  = (const int*)d_in[2];
    const float* pos_w  = (const float*)d_in[3];
    const float* pos_b  = (const float*)d_in[4];
    const float* w0     = (const float*)d_in[5];
    const float* asrc0  = (const float*)d_in[6];
    const float* adst0  = (const float*)d_in[7];
    const float* b0     = (const float*)d_in[8];
    const float* w1     = (const float*)d_in[9];
    const float* asrc1  = (const float*)d_in[10];
    const float* adst1  = (const float*)d_in[11];
    const float* b1     = (const float*)d_in[12];
    const float* bn_gamma = (const float*)d_in[13];
    const float* bn_beta  = (const float*)d_in[14];
    const float* bn_mean  = (const float*)d_in[15];
    const float* bn_var   = (const float*)d_in[16];
    const float* proj   = (const float*)d_in[17];
    const float* res_w  = (const float*)d_in[18];
    const float* res_b  = (const float*)d_in[19];
    const float* task_w = (const float*)d_in[20];
    const float* task_b = (const float*)d_in[21];
    float* out = (float*)d_out;

    // workspace layout
    unsigned short* wbT0 = (unsigned short*)d_ws;
    unsigned short* wbT1 = wbT0 + 128 * K0P;
    unsigned short* wbTr = wbT1 + 128 * 128;
    unsigned short* hb   = wbTr + 128 * 128;                   // N*128 bf16 (gemm out h)
    unsigned short* hb0  = hb + (size_t)N_NODES * 128;         // N*128 bf16 (layer0 act)
    unsigned short* bbuf = hb0 + (size_t)N_NODES * 128;        // N*128 bf16 (res proj)
    float* p = (float*)(bbuf + (size_t)N_NODES * 128);
    float* abuf = p; p += (size_t)N_NODES * D1;                // agg out (f32)
    float* es   = p; p += (size_t)N_NODES * 4;
    float* ed   = p; p += (size_t)N_NODES * 4;
    float2* pos2 = (float2*)p; p += (size_t)N_NODES * 2;
    float* emb  = p; p += G_GRAPHS * 128;
    float* Msum = p; p += 16;
    int* counts = (int*)p;
    int* starts  = counts + G_GRAPHS;
    int* gridg   = starts + G_GRAPHS;
    int* bcount  = gridg + G_GRAPHS;
    int* bstart  = bcount + NB;
    int* bcursor = bstart + NB + 1;
    int* offs    = bcursor + NB;
    int* csr_src = (int*)(((uintptr_t)(offs + N_NODES + 1) + 15) & ~(uintptr_t)15);
    int2* pairs  = (int2*)(csr_src + N_EDGES + 8);

    const int B = 256;

    hipMemsetAsync(counts, 0, G_GRAPHS * sizeof(int), stream);
    hipMemsetAsync(Msum, 0, 12 * sizeof(float), stream);
    hipMemsetAsync(bcount, 0, NB * sizeof(int), stream);
    hipMemsetAsync(emb, 0, G_GRAPHS * 128 * sizeof(float), stream);
    hipMemsetAsync(csr_src + N_EDGES, 0, 8 * sizeof(int), stream);
    k_hist<<<256, B, 0, stream>>>(batch, counts, N_NODES);
    k_gridstats<<<1, 64, 0, stream>>>(counts, starts, gridg);
    k_pos<<<(N_NODES + B - 1) / B, B, 0, stream>>>(batch, starts, gridg, pos2);
    k_wprep<<<(128 * K0P + 2 * 128 * 128 + 255) / 256, 256, 0, stream>>>(
        w0, w1, res_w, wbT0, wbT1, wbTr);

    // CSR build: bucketed two-pass sort
    k_bhist<<<(N_EDGES / 8 + B - 1) / B, B, 0, stream>>>(ei, bcount);
    k_bscan<<<1, 64, 0, stream>>>(bcount, bstart, bcursor);
    k_bucket<<<NTILES, B, 0, stream>>>(ei, bcursor, pairs);
    k_csr<<<NB, B, 0, stream>>>(pairs, bstart, offs, csr_src);

    const int GB = (N_NODES + 63) / 64;
    const int AB = (N_NODES + 3) / 4;

    // ---- layer 0 ----
    k_gemm3<K0P, 1, 0, 0><<<GB, 256, 0, stream>>>(
        x, nullptr, pos2, pos_w, pos_b, wbT0, asrc0, adst0, es, ed, hb,
        nullptr, nullptr, nullptr, N_NODES);
    k_aggb<<<AB, B, 0, stream>>>(csr_src, offs, es, ed, (const unsigned*)hb, b0, abuf);
    k_divbn<0><<<1024, B, 0, stream>>>(
        abuf, nullptr, proj, bn_gamma, bn_beta, bn_mean, bn_var, Msum,
        (unsigned*)hb0, nullptr, nullptr);

    // ---- layer 1 ----
    k_gemm3<D1, 0, 1, 1><<<GB, 256, 0, stream>>>(
        nullptr, hb0, nullptr, nullptr, nullptr, wbT1, asrc1, adst1, es, ed, hb,
        wbTr, res_b, bbuf, N_NODES);
    k_aggb<<<AB, B, 0, stream>>>(csr_src, offs, es, ed, (const unsigned*)hb, b1, abuf);
    k_divbn<1><<<1024, B, 0, stream>>>(
        abuf, (const unsigned*)bbuf, proj + HEADS * HID, bn_gamma + D1, bn_beta + D1,
        bn_mean + D1, bn_var + D1, Msum + 6, nullptr, batch, emb);

    // heads
    k_final<<<1, B, 0, stream>>>(emb, counts, task_w, task_b, Msum, out);
}

// Round 14
// 451.871 us; speedup vs baseline: 1.9120x; 1.0119x over previous
//
#include <hip/hip_runtime.h>
#include <hip/hip_bf16.h>

#define N_NODES 100000
#define N_EDGES 1600000
#define G_GRAPHS 64
#define D_IN 128
#define POS_DIM 16
#define HID 32
#define HEADS 4
#define OUT_DIM 10
#define D0 144
#define D1 128
#define LRELU_SLOPE 0.2f
#define BN_EPS 1e-5f
#define DIV_W 0.1f

#define BK_SHIFT 9
#define BK_NODES 512
#define NB 196
#define TILE_E 4096
#define NTILES ((N_EDGES + TILE_E - 1) / TILE_E)

#define K0P 160

typedef __attribute__((ext_vector_type(8))) short short8v;
typedef __attribute__((ext_vector_type(4))) float f32x4;

__device__ __forceinline__ unsigned short f2b(float f) {
    unsigned u = __float_as_uint(f);
    unsigned r = (u + 0x7FFFu + ((u >> 16) & 1u)) >> 16;
    return (unsigned short)r;
}
__device__ __forceinline__ float blo(unsigned v) { return __uint_as_float(v << 16); }
__device__ __forceinline__ float bhi(unsigned v) { return __uint_as_float(v & 0xFFFF0000u); }

// ---------------- histogram of batch -> counts[64] ----------------
__global__ void k_hist(const int* __restrict__ batch, int* __restrict__ counts, int n) {
    __shared__ int hist[G_GRAPHS];
    if (threadIdx.x < G_GRAPHS) hist[threadIdx.x] = 0;
    __syncthreads();
    for (int i = blockIdx.x * blockDim.x + threadIdx.x; i < n; i += gridDim.x * blockDim.x)
        atomicAdd(&hist[batch[i]], 1);
    __syncthreads();
    if (threadIdx.x < G_GRAPHS) atomicAdd(&counts[threadIdx.x], hist[threadIdx.x]);
}

__global__ void k_gridstats(const int* __restrict__ counts, int* __restrict__ starts,
                            int* __restrict__ gridg) {
    if (threadIdx.x == 0) {
        int run = 0;
        for (int g = 0; g < G_GRAPHS; ++g) {
            starts[g] = run;
            int c = counts[g];
            run += c;
            int s = (int)sqrtf((float)c);
            while ((long long)s * s < c) ++s;
            while (s > 0 && (long long)(s - 1) * (s - 1) >= c) --s;
            gridg[g] = s;
        }
    }
}

__global__ void k_pos(const int* __restrict__ batch, const int* __restrict__ starts,
                      const int* __restrict__ gridg, float2* __restrict__ pos2) {
    int t = blockIdx.x * blockDim.x + threadIdx.x;
    if (t >= N_NODES) return;
    int b = batch[t];
    int local = t - starts[b];
    int g = max(gridg[b], 1);
    float denom = (float)max(g - 1, 1);
    int r = local / g;
    int c = local - r * g;
    pos2[t] = make_float2((float)r / denom, (float)c / denom);
}

// ---------------- weight prep: bf16 transposed [col][K] ----------------
__global__ void k_wprep(const float* __restrict__ w0, const float* __restrict__ w1,
                        const float* __restrict__ wr, unsigned short* __restrict__ t0,
                        unsigned short* __restrict__ t1, unsigned short* __restrict__ tr) {
    int t = blockIdx.x * 256 + threadIdx.x;
    if (t < 128 * K0P) {
        int c = t / K0P, k = t % K0P;
        t0[t] = (k < D0) ? f2b(w0[k * 128 + c]) : (unsigned short)0;
    } else if (t < 128 * K0P + 128 * 128) {
        int i = t - 128 * K0P;
        int c = i / 128, k = i % 128;
        t1[i] = f2b(w1[k * 128 + c]);
    } else if (t < 128 * K0P + 2 * 128 * 128) {
        int i = t - 128 * K0P - 128 * 128;
        int c = i / 128, k = i % 128;
        tr[i] = f2b(wr[k * 128 + c]);
    }
}

// ---------------- bucket histogram over dst (x8 unrolled) ----------------
__global__ void k_bhist(const int* __restrict__ ei, int* __restrict__ bcount) {
    __shared__ int lh[256];
    int tid = threadIdx.x;
    lh[tid] = 0;
    __syncthreads();
    int e = (blockIdx.x * blockDim.x + tid) * 8;
    if (e < N_EDGES) {
        int4 d4 = *reinterpret_cast<const int4*>(ei + N_EDGES + e);
        int4 d5 = *reinterpret_cast<const int4*>(ei + N_EDGES + e + 4);
        atomicAdd(&lh[d4.x >> BK_SHIFT], 1);
        atomicAdd(&lh[d4.y >> BK_SHIFT], 1);
        atomicAdd(&lh[d4.z >> BK_SHIFT], 1);
        atomicAdd(&lh[d4.w >> BK_SHIFT], 1);
        atomicAdd(&lh[d5.x >> BK_SHIFT], 1);
        atomicAdd(&lh[d5.y >> BK_SHIFT], 1);
        atomicAdd(&lh[d5.z >> BK_SHIFT], 1);
        atomicAdd(&lh[d5.w >> BK_SHIFT], 1);
    }
    __syncthreads();
    if (tid < NB && lh[tid] > 0) atomicAdd(&bcount[tid], lh[tid]);
}

__global__ void k_bscan(const int* __restrict__ bcount, int* __restrict__ bstart,
                        int* __restrict__ bcursor) {
    if (threadIdx.x == 0) {
        int run = 0;
        for (int i = 0; i < NB; ++i) {
            bstart[i] = run;
            bcursor[i] = run;
            run += bcount[i];
        }
        bstart[NB] = run;
    }
}

// ---------------- tile-local counting sort -> bucket-major pairs (shfl scan) ----------------
__global__ __launch_bounds__(256) void k_bucket(const int* __restrict__ ei,
                                                int* __restrict__ bcursor,
                                                int2* __restrict__ pairs) {
    __shared__ int lh[256];
    __shared__ int lstart[256];
    __shared__ int lcur[256];
    __shared__ int gbase[256];
    __shared__ int wsum[4];
    __shared__ int2 stage[TILE_E];
    const int tid = threadIdx.x;
    const int lane = tid & 63;
    const int wid = tid >> 6;
    const int tile = blockIdx.x * TILE_E;
    const int cnt = min(TILE_E, N_EDGES - tile);
    lh[tid] = 0;
    __syncthreads();
    int sv[16], dv[16];
#pragma unroll
    for (int u = 0; u < 16; ++u) {
        int i = u * 256 + tid;
        if (i < cnt) {
            sv[u] = ei[tile + i];
            dv[u] = ei[N_EDGES + tile + i];
            atomicAdd(&lh[dv[u] >> BK_SHIFT], 1);
        } else {
            sv[u] = -1; dv[u] = -1;
        }
    }
    __syncthreads();
    int own = lh[tid];
    int incl = own;
#pragma unroll
    for (int off = 1; off < 64; off <<= 1) {
        int t = __shfl_up(incl, off, 64);
        if (lane >= off) incl += t;
    }
    if (lane == 63) wsum[wid] = incl;
    __syncthreads();
    int wo = 0;
#pragma unroll
    for (int w = 0; w < 3; ++w) if (w < wid) wo += wsum[w];
    int excl = incl - own + wo;
    lstart[tid] = excl;
    lcur[tid] = excl;
    __syncthreads();
#pragma unroll
    for (int u = 0; u < 16; ++u) {
        if (dv[u] >= 0) {
            int b = dv[u] >> BK_SHIFT;
            int slot = atomicAdd(&lcur[b], 1);
            stage[slot] = make_int2(sv[u], dv[u]);
        }
    }
    __syncthreads();
    if (tid < NB && own > 0) gbase[tid] = atomicAdd(&bcursor[tid], own);
    __syncthreads();
    for (int i = tid; i < cnt; i += 256) {
        int2 pr = stage[i];
        int b = pr.y >> BK_SHIFT;
        pairs[gbase[b] + (i - lstart[b])] = pr;
    }
}

// ---------------- per-bucket CSR finalize (shfl scan) ----------------
__global__ __launch_bounds__(256) void k_csr(const int2* __restrict__ pairs,
                                             const int* __restrict__ bstart,
                                             int* __restrict__ offs,
                                             int* __restrict__ csr_src) {
    __shared__ int ldeg[BK_NODES];
    __shared__ int lcur[BK_NODES];
    __shared__ int wsum[4];
    const int b = blockIdx.x;
    const int tid = threadIdx.x;
    const int lane = tid & 63;
    const int wid = tid >> 6;
    const int nb0 = b * BK_NODES;
    const int base = bstart[b];
    const int ecnt = bstart[b + 1] - base;
    ldeg[tid] = 0; ldeg[tid + 256] = 0;
    __syncthreads();
    for (int i = tid; i < ecnt; i += 256)
        atomicAdd(&ldeg[pairs[base + i].y - nb0], 1);
    __syncthreads();
    int v0 = ldeg[tid * 2], v1 = ldeg[tid * 2 + 1];
    int tsum = v0 + v1;
    int incl = tsum;
#pragma unroll
    for (int off = 1; off < 64; off <<= 1) {
        int t = __shfl_up(incl, off, 64);
        if (lane >= off) incl += t;
    }
    if (lane == 63) wsum[wid] = incl;
    __syncthreads();
    int wo = 0;
#pragma unroll
    for (int w = 0; w < 3; ++w) if (w < wid) wo += wsum[w];
    int excl = incl - tsum + wo;
    int o0 = base + excl;
    int o1 = o0 + v0;
    lcur[tid * 2] = o0;
    lcur[tid * 2 + 1] = o1;
    int n0 = nb0 + tid * 2, n1 = n0 + 1;
    if (n0 < N_NODES) offs[n0] = o0;
    if (n1 < N_NODES) offs[n1] = o1;
    if (b == NB - 1 && tid == 0) offs[N_NODES] = bstart[NB];
    __syncthreads();
    for (int i = tid; i < ecnt; i += 256) {
        int2 pr = pairs[base + i];
        int pos = atomicAdd(&lcur[pr.y - nb0], 1);
        csr_src[pos] = pr.x;
    }
}

// ---------------- MFMA GEMM: 64 rows x 128 cols / block ----------------
template <int K, int POS, int RES, int BF16A>
__global__ __launch_bounds__(256) void k_gemm3(
        const float* __restrict__ in, const unsigned short* __restrict__ inb,
        const float2* __restrict__ pos2,
        const float* __restrict__ posw, const float* __restrict__ posb,
        const unsigned short* __restrict__ wbT,
        const float* __restrict__ asrc, const float* __restrict__ adst,
        float* __restrict__ es, float* __restrict__ ed,
        unsigned short* __restrict__ outb,
        const unsigned short* __restrict__ wbT2, const float* __restrict__ bias2,
        unsigned short* __restrict__ outb2, int n) {
    __shared__ unsigned short At[64 * K];
    const int tid = threadIdx.x;
    const int base = blockIdx.x * 64;
    if (BF16A) {
        constexpr int KC8 = K / 8;
        for (int idx = tid; idx < 64 * KC8; idx += 256) {
            int row = idx / KC8, g = idx % KC8;
            int grow = base + row;
            short8v v = (short8v)(short)0;
            if (grow < n) v = *reinterpret_cast<const short8v*>(inb + (size_t)grow * 128 + g * 8);
            unsigned byteoff = (unsigned)((row * K + g * 8) * 2) ^ (unsigned)((row & 7) << 4);
            *reinterpret_cast<short8v*>(reinterpret_cast<char*>(At) + byteoff) = v;
        }
    } else {
        constexpr int KC4 = K / 4;
        for (int idx = tid; idx < 64 * KC4; idx += 256) {
            int row = idx / KC4, c4 = idx % KC4;
            int grow = base + row;
            float4 v = make_float4(0.f, 0.f, 0.f, 0.f);
            if (grow < n) {
                if (!POS || c4 < 32) {
                    v = reinterpret_cast<const float4*>(in)[(size_t)grow * 32 + c4];
                } else if (c4 < 36) {
                    float2 p = pos2[grow];
                    int q = c4 - 32;
                    float4 w0v = reinterpret_cast<const float4*>(posw)[q];
                    float4 w1v = reinterpret_cast<const float4*>(posw + POS_DIM)[q];
                    float4 bv  = reinterpret_cast<const float4*>(posb)[q];
                    v.x = fmaf(p.x, w0v.x, fmaf(p.y, w1v.x, bv.x));
                    v.y = fmaf(p.x, w0v.y, fmaf(p.y, w1v.y, bv.y));
                    v.z = fmaf(p.x, w0v.z, fmaf(p.y, w1v.z, bv.z));
                    v.w = fmaf(p.x, w0v.w, fmaf(p.y, w1v.w, bv.w));
                }
            }
            ushort4 b4;
            b4.x = f2b(v.x); b4.y = f2b(v.y); b4.z = f2b(v.z); b4.w = f2b(v.w);
            unsigned byteoff = (unsigned)((row * K + c4 * 4) * 2) ^ (unsigned)((row & 7) << 4);
            *reinterpret_cast<ushort4*>(reinterpret_cast<char*>(At) + byteoff) = b4;
        }
    }
    __syncthreads();

    const int wv = tid >> 6;
    const int lane = tid & 63;
    const int lrow = lane & 15;
    const int lk8 = lane >> 4;
    f32x4 acc[4][2];
    f32x4 acc2[RES ? 4 : 1][RES ? 2 : 1];
#pragma unroll
    for (int rt = 0; rt < 4; ++rt) {
#pragma unroll
        for (int ct = 0; ct < 2; ++ct) {
            acc[rt][ct] = (f32x4){0.f, 0.f, 0.f, 0.f};
            if (RES) acc2[rt][ct] = (f32x4){0.f, 0.f, 0.f, 0.f};
        }
    }
    const unsigned short* bp0 = wbT + (size_t)(wv * 32 + lrow) * K + lk8 * 8;
    const unsigned short* bp1 = bp0 + 16 * K;
    const unsigned short* cp0 = RES ? (wbT2 + (size_t)(wv * 32 + lrow) * K + lk8 * 8) : nullptr;
    const unsigned short* cp1 = RES ? cp0 + 16 * K : nullptr;

    for (int k0 = 0; k0 < K; k0 += 32) {
        short8v b0 = *reinterpret_cast<const short8v*>(bp0 + k0);
        short8v b1 = *reinterpret_cast<const short8v*>(bp1 + k0);
        short8v a[4];
#pragma unroll
        for (int rt = 0; rt < 4; ++rt) {
            int row = rt * 16 + lrow;
            unsigned byteoff = (unsigned)((row * K + k0 + lk8 * 8) * 2) ^ (unsigned)((row & 7) << 4);
            a[rt] = *reinterpret_cast<const short8v*>(reinterpret_cast<const char*>(At) + byteoff);
        }
#pragma unroll
        for (int rt = 0; rt < 4; ++rt) {
            acc[rt][0] = __builtin_amdgcn_mfma_f32_16x16x32_bf16(a[rt], b0, acc[rt][0], 0, 0, 0);
            acc[rt][1] = __builtin_amdgcn_mfma_f32_16x16x32_bf16(a[rt], b1, acc[rt][1], 0, 0, 0);
        }
        if (RES) {
            short8v c0 = *reinterpret_cast<const short8v*>(cp0 + k0);
            short8v c1 = *reinterpret_cast<const short8v*>(cp1 + k0);
#pragma unroll
            for (int rt = 0; rt < 4; ++rt) {
                acc2[rt][0] = __builtin_amdgcn_mfma_f32_16x16x32_bf16(a[rt], c0, acc2[rt][0], 0, 0, 0);
                acc2[rt][1] = __builtin_amdgcn_mfma_f32_16x16x32_bf16(a[rt], c1, acc2[rt][1], 0, 0, 0);
            }
        }
    }

    float av0 = asrc[wv * 32 + lrow], av1 = asrc[wv * 32 + 16 + lrow];
    float dv0 = adst[wv * 32 + lrow], dv1 = adst[wv * 32 + 16 + lrow];
    float bb0 = 0.f, bb1 = 0.f;
    if (RES) { bb0 = bias2[wv * 32 + lrow]; bb1 = bias2[wv * 32 + 16 + lrow]; }
#pragma unroll
    for (int rt = 0; rt < 4; ++rt) {
#pragma unroll
        for (int r = 0; r < 4; ++r) {
            int row = rt * 16 + lk8 * 4 + r;
            int grow = base + row;
            bool live = (grow < n);
            float v0 = acc[rt][0][r], v1 = acc[rt][1][r];
            if (live) {
                outb[(size_t)grow * 128 + wv * 32 + lrow] = f2b(v0);
                outb[(size_t)grow * 128 + wv * 32 + 16 + lrow] = f2b(v1);
                if (RES) {
                    outb2[(size_t)grow * 128 + wv * 32 + lrow] = f2b(acc2[rt][0][r] + bb0);
                    outb2[(size_t)grow * 128 + wv * 32 + 16 + lrow] = f2b(acc2[rt][1][r] + bb1);
                }
            }
            float ps = v0 * av0 + v1 * av1;
            float pd = v0 * dv0 + v1 * dv1;
            ps += __shfl_xor(ps, 1); pd += __shfl_xor(pd, 1);
            ps += __shfl_xor(ps, 2); pd += __shfl_xor(pd, 2);
            ps += __shfl_xor(ps, 4); pd += __shfl_xor(pd, 4);
            ps += __shfl_xor(ps, 8); pd += __shfl_xor(pd, 8);
            if (lrow == 0 && live) {
                es[grow * 4 + wv] = ps;
                ed[grow * 4 + wv] = pd;
            }
        }
    }
}

// ---------------- CSR aggregation: 1 node / wave, deduped exp via lane specialization ----
// lane l computes exp for (edge l&7, head (l>>3)&3); receivers shfl + mask.
__global__ void k_aggb(const int* __restrict__ csr_src, const int* __restrict__ offs,
                       const float* __restrict__ es, const float* __restrict__ ed,
                       const unsigned* __restrict__ hb32, const float* __restrict__ bias,
                       float* __restrict__ out) {
    int node = blockIdx.x * 4 + (threadIdx.x >> 6);
    if (node >= N_NODES) return;
    int lane = threadIdx.x & 63;
    int hd = lane >> 4;                  // head whose channels this lane owns
    int hh = (lane >> 3) & 3;            // head this lane computes exp for
    float4 edr = reinterpret_cast<const float4*>(ed)[node];
    float edh = (hh == 0) ? edr.x : (hh == 1) ? edr.y : (hh == 2) ? edr.z : edr.w;
    float edv = (hd == 0) ? edr.x : (hd == 1) ? edr.y : (hd == 2) ? edr.z : edr.w;
    int rs = offs[node], re_ = offs[node + 1];
    const int sl = hd << 3;              // shfl source base for this lane's head
    float ax[4] = {0.f, 0.f, 0.f, 0.f};
    float ay[4] = {0.f, 0.f, 0.f, 0.f};
    float ds[4] = {0.f, 0.f, 0.f, 0.f};
    for (int j = rs & ~7; j < re_; j += 8) {
        int4 c0 = *reinterpret_cast<const int4*>(csr_src + j);
        int4 c1 = *reinterpret_cast<const int4*>(csr_src + j + 4);
        int s[8] = {c0.x, c0.y, c0.z, c0.w, c1.x, c1.y, c1.z, c1.w};
        // unique (edge, head) exp on lanes 0..31 (32..63 duplicate)
        int su = (lane & 4) ? ((lane & 2) ? ((lane & 1) ? s[7] : s[6]) : ((lane & 1) ? s[5] : s[4]))
                            : ((lane & 2) ? ((lane & 1) ? s[3] : s[2]) : ((lane & 1) ? s[1] : s[0]));
        float a = es[su * 4 + hh] + edh;
        a = (a > 0.f) ? a : LRELU_SLOPE * a;
        float x = __expf(a);
        unsigned q[8];
#pragma unroll
        for (int u = 0; u < 8; ++u) q[u] = hb32[(size_t)s[u] * 64 + lane];
#pragma unroll
        for (int u = 0; u < 8; ++u) {
            float xu = __shfl(x, sl + u, 64);
            int idx = j + u;
            xu = (idx >= rs && idx < re_) ? xu : 0.f;
            ax[u & 3] = fmaf(xu, blo(q[u]), ax[u & 3]);
            ay[u & 3] = fmaf(xu, bhi(q[u]), ay[u & 3]);
            ds[u & 3] += xu;
        }
    }
    {   // self loop (own head)
        float a = es[node * 4 + hd] + edv;
        a = (a > 0.f) ? a : LRELU_SLOPE * a;
        float x = __expf(a);
        unsigned hv = hb32[(size_t)node * 64 + lane];
        ax[0] = fmaf(x, blo(hv), ax[0]);
        ay[0] = fmaf(x, bhi(hv), ay[0]);
        ds[0] += x;
    }
    float inv = 1.f / (ds[0] + ds[1] + ds[2] + ds[3]);
    float2 o;
    o.x = fmaf(ax[0] + ax[1] + ax[2] + ax[3], inv, bias[lane * 2]);
    o.y = fmaf(ay[0] + ay[1] + ay[2] + ay[3], inv, bias[lane * 2 + 1]);
    reinterpret_cast<float2*>(out)[(size_t)node * 64 + lane] = o;
}

// ---------------- div loss + BN + ELU; LAYER0 -> bf16 h0; LAYER1 -> +res, pool, no store --
template <int LAYER>
__global__ __launch_bounds__(256) void k_divbn(
        const float* __restrict__ hin, const unsigned* __restrict__ rbuf16,
        const float* __restrict__ proj, const float* __restrict__ gamma,
        const float* __restrict__ beta, const float* __restrict__ mean,
        const float* __restrict__ var, float* __restrict__ Msum,
        unsigned* __restrict__ outb16,
        const int* __restrict__ batch, float* __restrict__ emb) {
    __shared__ float sm[6];
    const int tid = threadIdx.x;
    if (tid < 6) sm[tid] = 0.f;
    __syncthreads();
    const int lane = tid & 63;
    const int wid = tid >> 6;
    const int wave_id = blockIdx.x * 4 + wid;
    const int CH = (N_NODES + 4095) / 4096;
    const int start = wave_id * CH;
    const int end = min(start + CH, N_NODES);
    float2 pj = reinterpret_cast<const float2*>(proj)[lane];
    float2 g2 = reinterpret_cast<const float2*>(gamma)[lane];
    float2 b2 = reinterpret_cast<const float2*>(beta)[lane];
    float2 m2 = reinterpret_cast<const float2*>(mean)[lane];
    float2 v2 = reinterpret_cast<const float2*>(var)[lane];
    float scx = g2.x * rsqrtf(v2.x + BN_EPS);
    float scy = g2.y * rsqrtf(v2.y + BN_EPS);
    float accA = 0.f, accB = 0.f, accC = 0.f;
    float ex = 0.f, ey = 0.f;
    int curg = -1;
    for (int node = start; node < end; ++node) {
        float2 hv = reinterpret_cast<const float2*>(hin)[(size_t)node * 64 + lane];
        float px = hv.x * pj.x, py = hv.y * pj.y;
        float nn = px * px + py * py;
        nn += __shfl_xor(nn, 1); nn += __shfl_xor(nn, 2);
        nn += __shfl_xor(nn, 4); nn += __shfl_xor(nn, 8);
        float tx = __shfl_xor(px, 16), ty = __shfl_xor(py, 16);
        float d16 = px * tx + py * ty;
        tx = __shfl_xor(px, 32); ty = __shfl_xor(py, 32);
        float d32 = px * tx + py * ty;
        tx = __shfl_xor(px, 48); ty = __shfl_xor(py, 48);
        float d48 = px * tx + py * ty;
        d16 += __shfl_xor(d16, 1); d16 += __shfl_xor(d16, 2);
        d16 += __shfl_xor(d16, 4); d16 += __shfl_xor(d16, 8);
        d32 += __shfl_xor(d32, 1); d32 += __shfl_xor(d32, 2);
        d32 += __shfl_xor(d32, 4); d32 += __shfl_xor(d32, 8);
        d48 += __shfl_xor(d48, 1); d48 += __shfl_xor(d48, 2);
        d48 += __shfl_xor(d48, 4); d48 += __shfl_xor(d48, 8);
        float n_own = fmaxf(sqrtf(nn), 1e-8f);
        float n16 = fmaxf(sqrtf(__shfl_xor(nn, 16)), 1e-8f);
        float n32 = fmaxf(sqrtf(__shfl_xor(nn, 32)), 1e-8f);
        float n48 = fmaxf(sqrtf(__shfl_xor(nn, 48)), 1e-8f);
        accA += d16 / (n_own * n16);
        accB += d32 / (n_own * n32);
        accC += d48 / (n_own * n48);
        float yx = (hv.x - m2.x) * scx + b2.x;
        float yy = (hv.y - m2.y) * scy + b2.y;
        yx = (yx > 0.f) ? yx : (__expf(yx) - 1.f);
        yy = (yy > 0.f) ? yy : (__expf(yy) - 1.f);
        if (LAYER == 1) {
            unsigned rb = rbuf16[(size_t)node * 64 + lane];
            yx += blo(rb);
            yy += bhi(rb);
            int g = batch[node];
            if (g != curg) {
                if (curg >= 0) {
                    unsafeAtomicAdd(&emb[curg * 128 + lane * 2], ex);
                    unsafeAtomicAdd(&emb[curg * 128 + lane * 2 + 1], ey);
                }
                curg = g; ex = 0.f; ey = 0.f;
            }
            ex += yx; ey += yy;
        } else {
            outb16[(size_t)node * 64 + lane] = (unsigned)f2b(yx) | ((unsigned)f2b(yy) << 16);
        }
    }
    if (LAYER == 1 && curg >= 0) {
        unsafeAtomicAdd(&emb[curg * 128 + lane * 2], ex);
        unsafeAtomicAdd(&emb[curg * 128 + lane * 2 + 1], ey);
    }
    int g = lane >> 4;
    if ((lane & 15) == 0) {
        if (g == 0) {
            atomicAdd(&sm[0], accA);
            atomicAdd(&sm[1], accB);
            atomicAdd(&sm[2], accC);
        } else if (g == 1) {
            atomicAdd(&sm[4], accB);
            atomicAdd(&sm[3], accC);
        } else if (g == 2) {
            atomicAdd(&sm[5], accA);
        }
    }
    __syncthreads();
    if (tid < 6) unsafeAtomicAdd(&Msum[tid], sm[tid]);
}

// ---------------- final: emb normalize, task head, div scalar ----------------
__global__ void k_final(const float* __restrict__ emb_ws, const int* __restrict__ counts,
                        const float* __restrict__ task_w, const float* __restrict__ task_b,
                        const float* __restrict__ Msum, float* __restrict__ out) {
    __shared__ float e_lds[G_GRAPHS * 128];
    __shared__ float cnt[G_GRAPHS];
    int tid = threadIdx.x;
    if (tid < G_GRAPHS) cnt[tid] = fmaxf((float)counts[tid], 1.f);
    __syncthreads();
    for (int i = tid; i < G_GRAPHS * 128; i += 256) {
        float v = emb_ws[i] / cnt[i >> 7];
        e_lds[i] = v;
        out[641 + i] = v;
    }
    __syncthreads();
    for (int p = tid; p < G_GRAPHS * OUT_DIM; p += 256) {
        int g = p / OUT_DIM, o = p % OUT_DIM;
        float acc = task_b[o];
#pragma unroll 8
        for (int k = 0; k < 128; ++k) acc = fmaf(e_lds[g * 128 + k], task_w[k * OUT_DIM + o], acc);
        out[p] = acc;
    }
    if (tid == 0) {
        float div = 0.f;
        for (int l = 0; l < 2; ++l) {
            float s = 0.f;
            for (int p = 0; p < 6; ++p) {
                float m = Msum[l * 6 + p] / (float)N_NODES;
                s = fmaf(m, m, s);
            }
            div += s / 6.f;
        }
        out[G_GRAPHS * OUT_DIM] = DIV_W * div;
    }
}

extern "C" void kernel_launch(void* const* d_in, const int* in_sizes, int n_in,
                              void* d_out, int out_size, void* d_ws, size_t ws_size,
                              hipStream_t stream) {
    const float* x      = (const float*)d_in[0];
    const int*   ei     = (const int*)d_in[1];
    const int*   batch  = (const int*)d_in[2];
    const float* pos_w  = (const float*)d_in[3];
    const float* pos_b  = (const float*)d_in[4];
    const float* w0     = (const float*)d_in[5];
    const float* asrc0  = (const float*)d_in[6];
    const float* adst0  = (const float*)d_in[7];
    const float* b0     = (const float*)d_in[8];
    const float* w1     = (const float*)d_in[9];
    const float* asrc1  = (const float*)d_in[10];
    const float* adst1  = (const float*)d_in[11];
    const float* b1     = (const float*)d_in[12];
    const float* bn_gamma = (const float*)d_in[13];
    const float* bn_beta  = (const float*)d_in[14];
    const float* bn_mean  = (const float*)d_in[15];
    const float* bn_var   = (const float*)d_in[16];
    const float* proj   = (const float*)d_in[17];
    const float* res_w  = (const float*)d_in[18];
    const float* res_b  = (const float*)d_in[19];
    const float* task_w = (const float*)d_in[20];
    const float* task_b = (const float*)d_in[21];
    float* out = (float*)d_out;

    // workspace layout
    unsigned short* wbT0 = (unsigned short*)d_ws;
    unsigned short* wbT1 = wbT0 + 128 * K0P;
    unsigned short* wbTr = wbT1 + 128 * 128;
    unsigned short* hb   = wbTr + 128 * 128;                   // N*128 bf16 (gemm out h)
    unsigned short* hb0  = hb + (size_t)N_NODES * 128;         // N*128 bf16 (layer0 act)
    unsigned short* bbuf = hb0 + (size_t)N_NODES * 128;        // N*128 bf16 (res proj)
    float* p = (float*)(bbuf + (size_t)N_NODES * 128);
    float* abuf = p; p += (size_t)N_NODES * D1;                // agg out (f32)
    float* es   = p; p += (size_t)N_NODES * 4;
    float* ed   = p; p += (size_t)N_NODES * 4;
    float2* pos2 = (float2*)p; p += (size_t)N_NODES * 2;
    float* emb  = p; p += G_GRAPHS * 128;
    float* Msum = p; p += 16;
    int* counts = (int*)p;
    int* starts  = counts + G_GRAPHS;
    int* gridg   = starts + G_GRAPHS;
    int* bcount  = gridg + G_GRAPHS;
    int* bstart  = bcount + NB;
    int* bcursor = bstart + NB + 1;
    int* offs    = bcursor + NB;
    int* csr_src = (int*)(((uintptr_t)(offs + N_NODES + 1) + 15) & ~(uintptr_t)15);
    int2* pairs  = (int2*)(csr_src + N_EDGES + 8);

    const int B = 256;

    hipMemsetAsync(counts, 0, G_GRAPHS * sizeof(int), stream);
    hipMemsetAsync(Msum, 0, 12 * sizeof(float), stream);
    hipMemsetAsync(bcount, 0, NB * sizeof(int), stream);
    hipMemsetAsync(emb, 0, G_GRAPHS * 128 * sizeof(float), stream);
    hipMemsetAsync(csr_src + N_EDGES, 0, 8 * sizeof(int), stream);
    k_hist<<<256, B, 0, stream>>>(batch, counts, N_NODES);
    k_gridstats<<<1, 64, 0, stream>>>(counts, starts, gridg);
    k_pos<<<(N_NODES + B - 1) / B, B, 0, stream>>>(batch, starts, gridg, pos2);
    k_wprep<<<(128 * K0P + 2 * 128 * 128 + 255) / 256, 256, 0, stream>>>(
        w0, w1, res_w, wbT0, wbT1, wbTr);

    // CSR build: bucketed two-pass sort
    k_bhist<<<(N_EDGES / 8 + B - 1) / B, B, 0, stream>>>(ei, bcount);
    k_bscan<<<1, 64, 0, stream>>>(bcount, bstart, bcursor);
    k_bucket<<<NTILES, B, 0, stream>>>(ei, bcursor, pairs);
    k_csr<<<NB, B, 0, stream>>>(pairs, bstart, offs, csr_src);

    const int GB = (N_NODES + 63) / 64;
    const int AB = (N_NODES + 3) / 4;

    // ---- layer 0 ----
    k_gemm3<K0P, 1, 0, 0><<<GB, 256, 0, stream>>>(
        x, nullptr, pos2, pos_w, pos_b, wbT0, asrc0, adst0, es, ed, hb,
        nullptr, nullptr, nullptr, N_NODES);
    k_aggb<<<AB, B, 0, stream>>>(csr_src, offs, es, ed, (const unsigned*)hb, b0, abuf);
    k_divbn<0><<<1024, B, 0, stream>>>(
        abuf, nullptr, proj, bn_gamma, bn_beta, bn_mean, bn_var, Msum,
        (unsigned*)hb0, nullptr, nullptr);

    // ---- layer 1 ----
    k_gemm3<D1, 0, 1, 1><<<GB, 256, 0, stream>>>(
        nullptr, hb0, nullptr, nullptr, nullptr, wbT1, asrc1, adst1, es, ed, hb,
        wbTr, res_b, bbuf, N_NODES);
    k_aggb<<<AB, B, 0, stream>>>(csr_src, offs, es, ed, (const unsigned*)hb, b1, abuf);
    k_divbn<1><<<1024, B, 0, stream>>>(
        abuf, (const unsigned*)bbuf, proj + HEADS * HID, bn_gamma + D1, bn_beta + D1,
        bn_mean + D1, bn_var + D1, Msum + 6, nullptr, batch, emb);

    // heads
    k_final<<<1, B, 0, stream>>>(emb, counts, task_w, task_b, Msum, out);
}